// Round 5
// baseline (246.733 us; speedup 1.0000x reference)
//
#include <hip/hip_runtime.h>
#include <hip/hip_bf16.h>

// Problem constants (B, C, T, H, KC, WIN) = (4, 512, 1024, 8, 64, 4)
#define Bdim 4
#define Cdim 512
#define Tdim 1024
#define Hn   8
#define KCd  64

typedef __attribute__((ext_vector_type(8))) short bf16x8;   // 8 bf16 = 4 VGPR
typedef __attribute__((ext_vector_type(4))) float f32x4;    // MFMA C/D

__device__ __forceinline__ unsigned short f32_bf16_rne(float f) {
    unsigned u = __float_as_uint(f);
    u += 0x7FFFu + ((u >> 16) & 1u);
    return (unsigned short)(u >> 16);
}
__device__ __forceinline__ float bf16_f32(unsigned short h) {
    return __uint_as_float(((unsigned)h) << 16);
}

// 64x64 bf16 tile, 16B-chunk XOR swizzle (row stride 128 B, chunk ^= row&7).
// Same image in global planes and in LDS -> staging is a straight copy.
__device__ __forceinline__ int sw(int row, int col) {
    return (row << 6) + ((((col >> 3) ^ (row & 7)) << 3) | (col & 7));
}
__device__ __forceinline__ bf16x8 fragld(const unsigned short* a, int row, int kstep, int quad) {
    return *(const bf16x8*)&a[(row << 6) + ((((kstep << 2) | quad) ^ (row & 7)) << 3)];
}

// ---------------------------------------------------------------------------
// bf16x3 MFMA GEMM: out[b,m,n] = sum_k W[m,k] * X[b,k,n] + bias[m]
// mode 0 (QKV): sel 0 (Q) and sel 1 (K) -> bf16 hi/lo planes, tiles [t][c];
//               sel 2 (V) -> bf16 hi/lo planes, tiles [c][t]. All swizzled.
// mode 1 (out-proj): natural fp32 [B,C,T] store.
// ---------------------------------------------------------------------------
#define BM 128
#define BN 64
#define BK 32
#define LDK 40

__global__ __launch_bounds__(256) void gemm3_mfma(
    int mode,
    const float* __restrict__ w0, const float* __restrict__ w1, const float* __restrict__ w2,
    const float* __restrict__ b0, const float* __restrict__ b1, const float* __restrict__ b2,
    const float* __restrict__ x,
    unsigned short* __restrict__ qhi, unsigned short* __restrict__ qlo,
    unsigned short* __restrict__ khi, unsigned short* __restrict__ klo,
    unsigned short* __restrict__ vhi, unsigned short* __restrict__ vlo,
    float* __restrict__ ofp)
{
    __shared__ unsigned short Whi[BM][LDK], Wlo[BM][LDK];
    __shared__ unsigned short Xhi[BN][LDK], Xlo[BN][LDK];

    const int tid = threadIdx.x;
    const int bx = blockIdx.x;
    const int by = blockIdx.y;
    const int b  = blockIdx.z;

    const int m_tile = by * BM;
    const int sel = m_tile >> 9;
    const float* W  = sel == 0 ? w0 : (sel == 1 ? w1 : w2);
    const float* Bv = sel == 0 ? b0 : (sel == 1 ? b1 : b2);
    const int m0 = m_tile & 511;
    const int n0 = bx * BN;

    const float* Xb = x + (size_t)b * Cdim * Tdim;

    const int lane = tid & 63, wid = tid >> 6;
    const int wm = (wid & 1) * 64, wn = (wid >> 1) * 32;
    const int l15 = lane & 15, quad = lane >> 4;

    const int wk4 = (tid & 7) * 4;
    const int wmr = tid >> 3;
    const int xn  = tid & 63;
    const int xo  = tid >> 6;

    f32x4 acc[4][2];
    #pragma unroll
    for (int i = 0; i < 4; ++i)
        #pragma unroll
        for (int j = 0; j < 2; ++j) acc[i][j] = (f32x4){0.f, 0.f, 0.f, 0.f};

    for (int k0 = 0; k0 < Cdim; k0 += BK) {
        __syncthreads();

        #pragma unroll
        for (int p = 0; p < 4; ++p) {
            const int m = wmr + p * 32;
            float4 wv = *(const float4*)(W + (size_t)(m0 + m) * Cdim + k0 + wk4);
            ushort4 hi, lo;
            hi.x = f32_bf16_rne(wv.x); lo.x = f32_bf16_rne(wv.x - bf16_f32(hi.x));
            hi.y = f32_bf16_rne(wv.y); lo.y = f32_bf16_rne(wv.y - bf16_f32(hi.y));
            hi.z = f32_bf16_rne(wv.z); lo.z = f32_bf16_rne(wv.z - bf16_f32(hi.z));
            hi.w = f32_bf16_rne(wv.w); lo.w = f32_bf16_rne(wv.w - bf16_f32(hi.w));
            *(ushort4*)&Whi[m][wk4] = hi;
            *(ushort4*)&Wlo[m][wk4] = lo;
        }

        {
            float xv[8];
            #pragma unroll
            for (int kk = 0; kk < 8; ++kk)
                xv[kk] = Xb[(size_t)(k0 + xo * 8 + kk) * Tdim + n0 + xn];
            ushort4 hi0, hi1, lo0, lo1;
            unsigned short h;
            h = f32_bf16_rne(xv[0]); hi0.x = h; lo0.x = f32_bf16_rne(xv[0] - bf16_f32(h));
            h = f32_bf16_rne(xv[1]); hi0.y = h; lo0.y = f32_bf16_rne(xv[1] - bf16_f32(h));
            h = f32_bf16_rne(xv[2]); hi0.z = h; lo0.z = f32_bf16_rne(xv[2] - bf16_f32(h));
            h = f32_bf16_rne(xv[3]); hi0.w = h; lo0.w = f32_bf16_rne(xv[3] - bf16_f32(h));
            h = f32_bf16_rne(xv[4]); hi1.x = h; lo1.x = f32_bf16_rne(xv[4] - bf16_f32(h));
            h = f32_bf16_rne(xv[5]); hi1.y = h; lo1.y = f32_bf16_rne(xv[5] - bf16_f32(h));
            h = f32_bf16_rne(xv[6]); hi1.z = h; lo1.z = f32_bf16_rne(xv[6] - bf16_f32(h));
            h = f32_bf16_rne(xv[7]); hi1.w = h; lo1.w = f32_bf16_rne(xv[7] - bf16_f32(h));
            *(ushort4*)&Xhi[xn][xo * 8]     = hi0;
            *(ushort4*)&Xhi[xn][xo * 8 + 4] = hi1;
            *(ushort4*)&Xlo[xn][xo * 8]     = lo0;
            *(ushort4*)&Xlo[xn][xo * 8 + 4] = lo1;
        }
        __syncthreads();

        bf16x8 ahi[4], alo[4], bhi[2], blo[2];
        #pragma unroll
        for (int mt = 0; mt < 4; ++mt) {
            ahi[mt] = *(const bf16x8*)&Whi[wm + mt * 16 + l15][quad * 8];
            alo[mt] = *(const bf16x8*)&Wlo[wm + mt * 16 + l15][quad * 8];
        }
        #pragma unroll
        for (int nt = 0; nt < 2; ++nt) {
            bhi[nt] = *(const bf16x8*)&Xhi[wn + nt * 16 + l15][quad * 8];
            blo[nt] = *(const bf16x8*)&Xlo[wn + nt * 16 + l15][quad * 8];
        }
        #pragma unroll
        for (int mt = 0; mt < 4; ++mt)
            #pragma unroll
            for (int nt = 0; nt < 2; ++nt) {
                f32x4 c = acc[mt][nt];
                c = __builtin_amdgcn_mfma_f32_16x16x32_bf16(ahi[mt], bhi[nt], c, 0, 0, 0);
                c = __builtin_amdgcn_mfma_f32_16x16x32_bf16(ahi[mt], blo[nt], c, 0, 0, 0);
                c = __builtin_amdgcn_mfma_f32_16x16x32_bf16(alo[mt], bhi[nt], c, 0, 0, 0);
                acc[mt][nt] = c;
            }
    }

    // ---- epilogue ----
    if (mode == 1) {
        float* Ob = ofp + (size_t)b * Cdim * Tdim;
        #pragma unroll
        for (int mt = 0; mt < 4; ++mt) {
            const int mb = m0 + wm + mt * 16 + quad * 4;
            float bb[4];
            #pragma unroll
            for (int r = 0; r < 4; ++r) bb[r] = Bv[mb + r];
            #pragma unroll
            for (int nt = 0; nt < 2; ++nt) {
                const int t = n0 + wn + nt * 16 + l15;
                #pragma unroll
                for (int r = 0; r < 4; ++r)
                    Ob[(size_t)(mb + r) * Tdim + t] = acc[mt][nt][r] + bb[r];
            }
        }
    } else if (sel < 2) {
        // Q/K planes: tiles [t&63][c], ushort4 along c (4 regs = 4 channels)
        unsigned short* phi = sel == 0 ? qhi : khi;
        unsigned short* plo = sel == 0 ? qlo : klo;
        #pragma unroll
        for (int mt = 0; mt < 4; ++mt) {
            const int mv = m0 + wm + mt * 16 + quad * 4;
            const int head = mv >> 6, c0 = mv & 63;
            float bb[4];
            #pragma unroll
            for (int r = 0; r < 4; ++r) bb[r] = Bv[mv + r];
            #pragma unroll
            for (int nt = 0; nt < 2; ++nt) {
                const int t = n0 + wn + nt * 16 + l15;
                const int tile = t >> 6, r_ = t & 63;
                const size_t off = (((size_t)(b * Hn + head) * 16 + tile) << 12)
                                 + (size_t)sw(r_, c0);
                ushort4 h4, l4;
                float v0 = acc[mt][nt][0] + bb[0];
                float v1 = acc[mt][nt][1] + bb[1];
                float v2 = acc[mt][nt][2] + bb[2];
                float v3 = acc[mt][nt][3] + bb[3];
                h4.x = f32_bf16_rne(v0); l4.x = f32_bf16_rne(v0 - bf16_f32(h4.x));
                h4.y = f32_bf16_rne(v1); l4.y = f32_bf16_rne(v1 - bf16_f32(h4.y));
                h4.z = f32_bf16_rne(v2); l4.z = f32_bf16_rne(v2 - bf16_f32(h4.z));
                h4.w = f32_bf16_rne(v3); l4.w = f32_bf16_rne(v3 - bf16_f32(h4.w));
                *(ushort4*)(phi + off) = h4;
                *(ushort4*)(plo + off) = l4;
            }
        }
    } else {
        // V planes: tiles [c][t&63] -> per-element ushort stores (transposed)
        #pragma unroll
        for (int mt = 0; mt < 4; ++mt) {
            const int mv = m0 + wm + mt * 16 + quad * 4;
            const int head = mv >> 6;
            float bb[4];
            #pragma unroll
            for (int r = 0; r < 4; ++r) bb[r] = Bv[mv + r];
            #pragma unroll
            for (int nt = 0; nt < 2; ++nt) {
                const int t = n0 + wn + nt * 16 + l15;
                const int tile = t >> 6, jl = t & 63;
                const size_t tb = ((size_t)(b * Hn + head) * 16 + tile) << 12;
                #pragma unroll
                for (int r = 0; r < 4; ++r) {
                    const int cr = (mv & 63) + r;
                    const float v = acc[mt][nt][r] + bb[r];
                    const unsigned short h = f32_bf16_rne(v);
                    const size_t off = tb + sw(cr, jl);
                    vhi[off] = h;
                    vlo[off] = f32_bf16_rne(v - bf16_f32(h));
                }
            }
        }
    }
}

// ---------------------------------------------------------------------------
// MFMA flash attention. All operands arrive as pre-split, pre-swizzled bf16
// hi/lo tile planes -> staging is a pure uint4 copy. Q frags load straight
// from global (no Q LDS); rk = q·ek via 6 MFMAs + tiny LDS round-trip.
// LDS = 53760 B -> up to 3 blocks/CU.
// ---------------------------------------------------------------------------
__global__ __launch_bounds__(256) void attn_mfma(
    const unsigned short* __restrict__ qhi, const unsigned short* __restrict__ qlo,
    const unsigned short* __restrict__ khi, const unsigned short* __restrict__ klo,
    const unsigned short* __restrict__ vhi, const unsigned short* __restrict__ vlo,
    const float* __restrict__ ek,   // [9,64]
    const float* __restrict__ ev,   // [9,64]
    float* __restrict__ ctx)        // [B,C,T]
{
    __shared__ alignas(16) unsigned short ksh[4096], ksl[4096];
    __shared__ alignas(16) unsigned short vsh[4096], vsl[4096];
    __shared__ alignas(16) unsigned short psh[4096], psl[4096];
    __shared__ float rk[576];       // [m][e], stride 9
    __shared__ float evs[576];      // [e][c]

    const int tid = threadIdx.x;
    const int it = blockIdx.x;      // i-tile (64 q rows)
    const int h = blockIdx.y, b = blockIdx.z;
    const int i0 = it * 64;
    const int lane = tid & 63, w = tid >> 6;
    const int l15 = lane & 15, quad = lane >> 4;
    const int m_blk = w * 16 + l15;

    const size_t bh16 = (size_t)(b * Hn + h) * 16;
    float* ctxb = ctx + ((size_t)b * Cdim + h * KCd) * Tdim;

    // ---- Q frags straight from global (one-time) ----
    bf16x8 qfh[2], qfl[2];
    {
        const unsigned short* qth = qhi + ((bh16 + it) << 12);
        const unsigned short* qtl = qlo + ((bh16 + it) << 12);
        #pragma unroll
        for (int ks = 0; ks < 2; ++ks) {
            const int off = (m_blk << 6) + ((((ks << 2) | quad) ^ (m_blk & 7)) << 3);
            qfh[ks] = *(const bf16x8*)(qth + off);
            qfl[ks] = *(const bf16x8*)(qtl + off);
        }
    }

    // ---- ek B-frags in registers (lanes l15>=9 zero) ----
    bf16x8 ekh[2], ekl[2];
    #pragma unroll
    for (int ks = 0; ks < 2; ++ks) {
        #pragma unroll
        for (int j = 0; j < 8; ++j) { ekh[ks][j] = 0; ekl[ks][j] = 0; }
        if (l15 < 9) {
            #pragma unroll
            for (int j = 0; j < 8; ++j) {
                const float v = ek[l15 * 64 + ks * 32 + quad * 8 + j];
                const unsigned short hh = f32_bf16_rne(v);
                ekh[ks][j] = (short)hh;
                ekl[ks][j] = (short)f32_bf16_rne(v - bf16_f32(hh));
            }
        }
    }

    // ---- rk[m][e] = q[m]·ek[e] via MFMA (raw, pre-scale) ----
    {
        f32x4 rkD = (f32x4){0.f, 0.f, 0.f, 0.f};
        #pragma unroll
        for (int ks = 0; ks < 2; ++ks) {
            rkD = __builtin_amdgcn_mfma_f32_16x16x32_bf16(qfh[ks], ekh[ks], rkD, 0, 0, 0);
            rkD = __builtin_amdgcn_mfma_f32_16x16x32_bf16(qfh[ks], ekl[ks], rkD, 0, 0, 0);
            rkD = __builtin_amdgcn_mfma_f32_16x16x32_bf16(qfl[ks], ekh[ks], rkD, 0, 0, 0);
        }
        if (l15 < 9) {
            #pragma unroll
            for (int r = 0; r < 4; ++r)
                rk[(w * 16 + quad * 4 + r) * 9 + l15] = rkD[r];
        }
    }
    for (int idx = tid; idx < 576; idx += 256) evs[idx] = ev[idx];

    float m_run = -1e30f, l_run = 0.f;
    f32x4 Oc[4];
    #pragma unroll
    for (int ct = 0; ct < 4; ++ct) Oc[ct] = (f32x4){0.f, 0.f, 0.f, 0.f};

    // ---- prefetch tile 0 (pure copies) ----
    const unsigned short* kh0 = khi + (bh16 << 12);
    const unsigned short* kl0 = klo + (bh16 << 12);
    const unsigned short* vh0 = vhi + (bh16 << 12);
    const unsigned short* vl0 = vlo + (bh16 << 12);
    uint4 kp[4], vp[4];
    kp[0] = *(const uint4*)(kh0 + tid * 8);
    kp[1] = *(const uint4*)(kh0 + (tid + 256) * 8);
    kp[2] = *(const uint4*)(kl0 + tid * 8);
    kp[3] = *(const uint4*)(kl0 + (tid + 256) * 8);
    vp[0] = *(const uint4*)(vh0 + tid * 8);
    vp[1] = *(const uint4*)(vh0 + (tid + 256) * 8);
    vp[2] = *(const uint4*)(vl0 + tid * 8);
    vp[3] = *(const uint4*)(vl0 + (tid + 256) * 8);

    for (int t = 0; t < 16; ++t) {
        const int j0 = t << 6;
        __syncthreads();   // prev GEMM2/rel-v LDS reads done (t=0: rk/evs writes)
        *(uint4*)&ksh[tid * 8] = kp[0];
        *(uint4*)&ksh[(tid + 256) * 8] = kp[1];
        *(uint4*)&ksl[tid * 8] = kp[2];
        *(uint4*)&ksl[(tid + 256) * 8] = kp[3];
        *(uint4*)&vsh[tid * 8] = vp[0];
        *(uint4*)&vsh[(tid + 256) * 8] = vp[1];
        *(uint4*)&vsl[tid * 8] = vp[2];
        *(uint4*)&vsl[(tid + 256) * 8] = vp[3];
        __syncthreads();   // K/V tile visible

        if (t < 15) {
            const size_t tb = (size_t)(t + 1) << 12;
            kp[0] = *(const uint4*)(kh0 + tb + tid * 8);
            kp[1] = *(const uint4*)(kh0 + tb + (tid + 256) * 8);
            kp[2] = *(const uint4*)(kl0 + tb + tid * 8);
            kp[3] = *(const uint4*)(kl0 + tb + (tid + 256) * 8);
            vp[0] = *(const uint4*)(vh0 + tb + tid * 8);
            vp[1] = *(const uint4*)(vh0 + tb + (tid + 256) * 8);
            vp[2] = *(const uint4*)(vl0 + tb + tid * 8);
            vp[3] = *(const uint4*)(vl0 + tb + (tid + 256) * 8);
        }

        // ---- GEMM1: S^T[j][m] (lane col = m_blk, rows j) ----
        f32x4 Sc[4];
        #pragma unroll
        for (int jt = 0; jt < 4; ++jt) Sc[jt] = (f32x4){0.f, 0.f, 0.f, 0.f};
        #pragma unroll
        for (int ks = 0; ks < 2; ++ks) {
            #pragma unroll
            for (int jt = 0; jt < 4; ++jt) {
                bf16x8 ah = fragld(ksh, jt * 16 + l15, ks, quad);
                bf16x8 al = fragld(ksl, jt * 16 + l15, ks, quad);
                Sc[jt] = __builtin_amdgcn_mfma_f32_16x16x32_bf16(ah, qfh[ks], Sc[jt], 0, 0, 0);
                Sc[jt] = __builtin_amdgcn_mfma_f32_16x16x32_bf16(ah, qfl[ks], Sc[jt], 0, 0, 0);
                Sc[jt] = __builtin_amdgcn_mfma_f32_16x16x32_bf16(al, qfh[ks], Sc[jt], 0, 0, 0);
            }
        }

        const int dt = j0 - i0;
        const bool diag = (dt >= -67 && dt <= 67);
        if (diag) {
            #pragma unroll
            for (int jt = 0; jt < 4; ++jt) {
                const int db = dt + jt * 16 + quad * 4 - m_blk;
                #pragma unroll
                for (int r = 0; r < 4; ++r) {
                    const int d = db + r;
                    if ((unsigned)(d + 4) <= 8u) Sc[jt][r] += rk[m_blk * 9 + d + 4];
                }
            }
        }

        // ---- scale + online softmax (per-lane row m_blk) ----
        float mt = -1e30f;
        #pragma unroll
        for (int jt = 0; jt < 4; ++jt)
            #pragma unroll
            for (int r = 0; r < 4; ++r) {
                Sc[jt][r] *= 0.125f;
                mt = fmaxf(mt, Sc[jt][r]);
            }
        mt = fmaxf(mt, __shfl_xor(mt, 16));
        mt = fmaxf(mt, __shfl_xor(mt, 32));
        const float mn = fmaxf(m_run, mt);
        const float alpha = __expf(m_run - mn);
        float rs = 0.f;
        #pragma unroll
        for (int jt = 0; jt < 4; ++jt)
            #pragma unroll
            for (int r = 0; r < 4; ++r) {
                const float e = __expf(Sc[jt][r] - mn);
                Sc[jt][r] = e;
                rs += e;
            }
        rs += __shfl_xor(rs, 16);
        rs += __shfl_xor(rs, 32);
        l_run = l_run * alpha + rs;
        m_run = mn;

        // ---- write P (A-layout [m][j], hi/lo) ----
        #pragma unroll
        for (int jt = 0; jt < 4; ++jt) {
            ushort4 ph, pl;
            ph.x = f32_bf16_rne(Sc[jt][0]); pl.x = f32_bf16_rne(Sc[jt][0] - bf16_f32(ph.x));
            ph.y = f32_bf16_rne(Sc[jt][1]); pl.y = f32_bf16_rne(Sc[jt][1] - bf16_f32(ph.y));
            ph.z = f32_bf16_rne(Sc[jt][2]); pl.z = f32_bf16_rne(Sc[jt][2] - bf16_f32(ph.z));
            ph.w = f32_bf16_rne(Sc[jt][3]); pl.w = f32_bf16_rne(Sc[jt][3] - bf16_f32(ph.w));
            const int o = sw(m_blk, jt * 16 + quad * 4);
            *(ushort4*)&psh[o] = ph;
            *(ushort4*)&psl[o] = pl;
        }
        __syncthreads();   // P visible

        // ---- GEMM2: O[m][c] += P·V, alpha-rescale first ----
        const float al0 = __shfl(alpha, quad * 4 + 0);
        const float al1 = __shfl(alpha, quad * 4 + 1);
        const float al2 = __shfl(alpha, quad * 4 + 2);
        const float al3 = __shfl(alpha, quad * 4 + 3);
        #pragma unroll
        for (int ct = 0; ct < 4; ++ct) {
            Oc[ct][0] *= al0; Oc[ct][1] *= al1; Oc[ct][2] *= al2; Oc[ct][3] *= al3;
        }
        #pragma unroll
        for (int ks = 0; ks < 2; ++ks) {
            bf16x8 pah = fragld(psh, m_blk, ks, quad);
            bf16x8 pal = fragld(psl, m_blk, ks, quad);
            #pragma unroll
            for (int ct = 0; ct < 4; ++ct) {
                bf16x8 bh = fragld(vsh, ct * 16 + l15, ks, quad);
                bf16x8 bl = fragld(vsl, ct * 16 + l15, ks, quad);
                Oc[ct] = __builtin_amdgcn_mfma_f32_16x16x32_bf16(pah, bh, Oc[ct], 0, 0, 0);
                Oc[ct] = __builtin_amdgcn_mfma_f32_16x16x32_bf16(pah, bl, Oc[ct], 0, 0, 0);
                Oc[ct] = __builtin_amdgcn_mfma_f32_16x16x32_bf16(pal, bh, Oc[ct], 0, 0, 0);
            }
        }

        if (diag) {   // banded rel-v via P in LDS
            #pragma unroll
            for (int r = 0; r < 4; ++r) {
                const int mrow = w * 16 + quad * 4 + r;
                const int ig = i0 + mrow;
                #pragma unroll
                for (int e = 0; e < 9; ++e) {
                    const int jl = ig + e - 4 - j0;
                    if ((unsigned)jl < 64u) {
                        const int o = sw(mrow, jl);
                        const float p = bf16_f32(psh[o]) + bf16_f32(psl[o]);
                        #pragma unroll
                        for (int ct = 0; ct < 4; ++ct)
                            Oc[ct][r] += p * evs[e * 64 + ct * 16 + l15];
                    }
                }
            }
        }
    }

    // ---- epilogue: normalize rows, store ctx natural [B,C,T] ----
    const float rlv = 1.f / l_run;
    const float rl0 = __shfl(rlv, quad * 4 + 0);
    const float rl1 = __shfl(rlv, quad * 4 + 1);
    const float rl2 = __shfl(rlv, quad * 4 + 2);
    const float rl3 = __shfl(rlv, quad * 4 + 3);
    #pragma unroll
    for (int ct = 0; ct < 4; ++ct) {
        float4 o4;
        o4.x = Oc[ct][0] * rl0;
        o4.y = Oc[ct][1] * rl1;
        o4.z = Oc[ct][2] * rl2;
        o4.w = Oc[ct][3] * rl3;
        *(float4*)(ctxb + (size_t)(ct * 16 + l15) * Tdim + i0 + w * 16 + quad * 4) = o4;
    }
}

// ---------------------------------------------------------------------------
extern "C" void kernel_launch(void* const* d_in, const int* in_sizes, int n_in,
                              void* d_out, int out_size, void* d_ws, size_t ws_size,
                              hipStream_t stream) {
    const float* x  = (const float*)d_in[0];
    const float* wq = (const float*)d_in[1];
    const float* bq = (const float*)d_in[2];
    const float* wk = (const float*)d_in[3];
    const float* bk = (const float*)d_in[4];
    const float* wv = (const float*)d_in[5];
    const float* bv = (const float*)d_in[6];
    const float* wo = (const float*)d_in[7];
    const float* bo = (const float*)d_in[8];
    const float* ek = (const float*)d_in[9];
    const float* ev = (const float*)d_in[10];
    float* out = (float*)d_out;

    const size_t plane = (size_t)Bdim * Cdim * Tdim;  // 2M elements
    unsigned short* qhi = (unsigned short*)d_ws;
    unsigned short* qlo = qhi + plane;
    unsigned short* khi = qlo + plane;
    unsigned short* klo = khi + plane;
    unsigned short* vhi = klo + plane;
    unsigned short* vlo = vhi + plane;
    float* cbuf = (float*)(vlo + plane);              // 8 MB fp32

    // QKV projection -> pre-split, pre-swizzled bf16 tile planes
    gemm3_mfma<<<dim3(Tdim / BN, 1536 / BM, Bdim), 256, 0, stream>>>(
        0, wq, wk, wv, bq, bk, bv, x, qhi, qlo, khi, klo, vhi, vlo, nullptr);

    // MFMA flash attention with banded relative terms
    attn_mfma<<<dim3(Tdim / 64, Hn, Bdim), 256, 0, stream>>>(
        qhi, qlo, khi, klo, vhi, vlo, ek, ev, cbuf);

    // output projection (natural fp32 store)
    gemm3_mfma<<<dim3(Tdim / BN, Cdim / BM, Bdim), 256, 0, stream>>>(
        1, wo, wo, wo, bo, bo, bo, cbuf,
        nullptr, nullptr, nullptr, nullptr, nullptr, nullptr, out);
}

// Round 6
// 238.873 us; speedup vs baseline: 1.0329x; 1.0329x over previous
//
#include <hip/hip_runtime.h>
#include <hip/hip_bf16.h>

// Problem constants (B, C, T, H, KC, WIN) = (4, 512, 1024, 8, 64, 4)
#define Bdim 4
#define Cdim 512
#define Tdim 1024
#define Hn   8
#define KCd  64

typedef __attribute__((ext_vector_type(8))) short bf16x8;   // 8 bf16 = 4 VGPR
typedef __attribute__((ext_vector_type(4))) float f32x4;    // MFMA C/D

__device__ __forceinline__ unsigned short f32_bf16_rne(float f) {
    unsigned u = __float_as_uint(f);
    u += 0x7FFFu + ((u >> 16) & 1u);
    return (unsigned short)(u >> 16);
}
__device__ __forceinline__ float bf16_f32(unsigned short h) {
    return __uint_as_float(((unsigned)h) << 16);
}

// 64x64 bf16 tile, 16B-chunk XOR swizzle (row stride 128 B, chunk ^= row&7).
// Same image in global planes and in LDS -> staging is a straight copy.
__device__ __forceinline__ int sw(int row, int col) {
    return (row << 6) + ((((col >> 3) ^ (row & 7)) << 3) | (col & 7));
}
__device__ __forceinline__ bf16x8 fragld(const unsigned short* a, int row, int kstep, int quad) {
    return *(const bf16x8*)&a[(row << 6) + ((((kstep << 2) | quad) ^ (row & 7)) << 3)];
}

// ---------------------------------------------------------------------------
// bf16x3 MFMA GEMM: out[b,m,n] = sum_k W[m,k] * X[b,k,n] + bias[m]
// mode 0 (QKV): sel 0 (Q) and sel 1 (K) -> bf16 hi/lo planes, tiles [t][c];
//               sel 2 (V) -> bf16 hi/lo planes, tiles [c][t]. All swizzled.
// mode 1 (out-proj): natural fp32 [B,C,T] store.
// Flat 1D grid with XCD-clustered decode: all m-blocks sharing an X k-stripe
// (b,bx) land on the same XCD (id%8 -> XCD round-robin heuristic) so the
// stripe is fetched into that XCD's L2 once.
// ---------------------------------------------------------------------------
#define BM 128
#define BN 64
#define BK 32
#define LDK 40

__global__ __launch_bounds__(256) void gemm3_mfma(
    int mode,
    const float* __restrict__ w0, const float* __restrict__ w1, const float* __restrict__ w2,
    const float* __restrict__ b0, const float* __restrict__ b1, const float* __restrict__ b2,
    const float* __restrict__ x,
    unsigned short* __restrict__ qhi, unsigned short* __restrict__ qlo,
    unsigned short* __restrict__ khi, unsigned short* __restrict__ klo,
    unsigned short* __restrict__ vhi, unsigned short* __restrict__ vlo,
    float* __restrict__ ofp)
{
    __shared__ unsigned short Whi[BM][LDK], Wlo[BM][LDK];
    __shared__ unsigned short Xhi[BN][LDK], Xlo[BN][LDK];

    const int tid = threadIdx.x;

    // ---- XCD-clustered decode ----
    int bx, by, b;
    {
        const int n = blockIdx.x;
        const int xcd = n & 7, slot = n >> 3;
        if (mode == 0) {
            // 768 blocks: 96 slots/XCD = 8 stripes x 12 m-blocks
            const int stripe = (xcd << 3) | (slot / 12);   // 0..63 = (b,bx)
            by = slot % 12;
            bx = stripe & 15;
            b  = stripe >> 4;
        } else {
            // 256 blocks: 32 slots/XCD = 8 stripes x 4 m-blocks
            const int stripe = (xcd << 3) | (slot >> 2);
            by = slot & 3;
            bx = stripe & 15;
            b  = stripe >> 4;
        }
    }

    const int m_tile = by * BM;
    const int sel = m_tile >> 9;
    const float* W  = sel == 0 ? w0 : (sel == 1 ? w1 : w2);
    const float* Bv = sel == 0 ? b0 : (sel == 1 ? b1 : b2);
    const int m0 = m_tile & 511;
    const int n0 = bx * BN;

    const float* Xb = x + (size_t)b * Cdim * Tdim;

    const int lane = tid & 63, wid = tid >> 6;
    const int wm = (wid & 1) * 64, wn = (wid >> 1) * 32;
    const int l15 = lane & 15, quad = lane >> 4;

    const int wk4 = (tid & 7) * 4;
    const int wmr = tid >> 3;
    const int xn  = tid & 63;
    const int xo  = tid >> 6;

    f32x4 acc[4][2];
    #pragma unroll
    for (int i = 0; i < 4; ++i)
        #pragma unroll
        for (int j = 0; j < 2; ++j) acc[i][j] = (f32x4){0.f, 0.f, 0.f, 0.f};

    for (int k0 = 0; k0 < Cdim; k0 += BK) {
        __syncthreads();

        #pragma unroll
        for (int p = 0; p < 4; ++p) {
            const int m = wmr + p * 32;
            float4 wv = *(const float4*)(W + (size_t)(m0 + m) * Cdim + k0 + wk4);
            ushort4 hi, lo;
            hi.x = f32_bf16_rne(wv.x); lo.x = f32_bf16_rne(wv.x - bf16_f32(hi.x));
            hi.y = f32_bf16_rne(wv.y); lo.y = f32_bf16_rne(wv.y - bf16_f32(hi.y));
            hi.z = f32_bf16_rne(wv.z); lo.z = f32_bf16_rne(wv.z - bf16_f32(hi.z));
            hi.w = f32_bf16_rne(wv.w); lo.w = f32_bf16_rne(wv.w - bf16_f32(hi.w));
            *(ushort4*)&Whi[m][wk4] = hi;
            *(ushort4*)&Wlo[m][wk4] = lo;
        }

        {
            float xv[8];
            #pragma unroll
            for (int kk = 0; kk < 8; ++kk)
                xv[kk] = Xb[(size_t)(k0 + xo * 8 + kk) * Tdim + n0 + xn];
            ushort4 hi0, hi1, lo0, lo1;
            unsigned short h;
            h = f32_bf16_rne(xv[0]); hi0.x = h; lo0.x = f32_bf16_rne(xv[0] - bf16_f32(h));
            h = f32_bf16_rne(xv[1]); hi0.y = h; lo0.y = f32_bf16_rne(xv[1] - bf16_f32(h));
            h = f32_bf16_rne(xv[2]); hi0.z = h; lo0.z = f32_bf16_rne(xv[2] - bf16_f32(h));
            h = f32_bf16_rne(xv[3]); hi0.w = h; lo0.w = f32_bf16_rne(xv[3] - bf16_f32(h));
            h = f32_bf16_rne(xv[4]); hi1.x = h; lo1.x = f32_bf16_rne(xv[4] - bf16_f32(h));
            h = f32_bf16_rne(xv[5]); hi1.y = h; lo1.y = f32_bf16_rne(xv[5] - bf16_f32(h));
            h = f32_bf16_rne(xv[6]); hi1.z = h; lo1.z = f32_bf16_rne(xv[6] - bf16_f32(h));
            h = f32_bf16_rne(xv[7]); hi1.w = h; lo1.w = f32_bf16_rne(xv[7] - bf16_f32(h));
            *(ushort4*)&Xhi[xn][xo * 8]     = hi0;
            *(ushort4*)&Xhi[xn][xo * 8 + 4] = hi1;
            *(ushort4*)&Xlo[xn][xo * 8]     = lo0;
            *(ushort4*)&Xlo[xn][xo * 8 + 4] = lo1;
        }
        __syncthreads();

        bf16x8 ahi[4], alo[4], bhi[2], blo[2];
        #pragma unroll
        for (int mt = 0; mt < 4; ++mt) {
            ahi[mt] = *(const bf16x8*)&Whi[wm + mt * 16 + l15][quad * 8];
            alo[mt] = *(const bf16x8*)&Wlo[wm + mt * 16 + l15][quad * 8];
        }
        #pragma unroll
        for (int nt = 0; nt < 2; ++nt) {
            bhi[nt] = *(const bf16x8*)&Xhi[wn + nt * 16 + l15][quad * 8];
            blo[nt] = *(const bf16x8*)&Xlo[wn + nt * 16 + l15][quad * 8];
        }
        #pragma unroll
        for (int mt = 0; mt < 4; ++mt)
            #pragma unroll
            for (int nt = 0; nt < 2; ++nt) {
                f32x4 c = acc[mt][nt];
                c = __builtin_amdgcn_mfma_f32_16x16x32_bf16(ahi[mt], bhi[nt], c, 0, 0, 0);
                c = __builtin_amdgcn_mfma_f32_16x16x32_bf16(ahi[mt], blo[nt], c, 0, 0, 0);
                c = __builtin_amdgcn_mfma_f32_16x16x32_bf16(alo[mt], bhi[nt], c, 0, 0, 0);
                acc[mt][nt] = c;
            }
    }

    // ---- epilogue ----
    if (mode == 1) {
        float* Ob = ofp + (size_t)b * Cdim * Tdim;
        #pragma unroll
        for (int mt = 0; mt < 4; ++mt) {
            const int mb = m0 + wm + mt * 16 + quad * 4;
            float bb[4];
            #pragma unroll
            for (int r = 0; r < 4; ++r) bb[r] = Bv[mb + r];
            #pragma unroll
            for (int nt = 0; nt < 2; ++nt) {
                const int t = n0 + wn + nt * 16 + l15;
                #pragma unroll
                for (int r = 0; r < 4; ++r)
                    Ob[(size_t)(mb + r) * Tdim + t] = acc[mt][nt][r] + bb[r];
            }
        }
    } else if (sel < 2) {
        // Q/K planes: tiles [t&63][c], ushort4 along c (4 regs = 4 channels)
        unsigned short* phi = sel == 0 ? qhi : khi;
        unsigned short* plo = sel == 0 ? qlo : klo;
        #pragma unroll
        for (int mt = 0; mt < 4; ++mt) {
            const int mv = m0 + wm + mt * 16 + quad * 4;
            const int head = mv >> 6, c0 = mv & 63;
            float bb[4];
            #pragma unroll
            for (int r = 0; r < 4; ++r) bb[r] = Bv[mv + r];
            #pragma unroll
            for (int nt = 0; nt < 2; ++nt) {
                const int t = n0 + wn + nt * 16 + l15;
                const int tile = t >> 6, r_ = t & 63;
                const size_t off = (((size_t)(b * Hn + head) * 16 + tile) << 12)
                                 + (size_t)sw(r_, c0);
                ushort4 h4, l4;
                float v0 = acc[mt][nt][0] + bb[0];
                float v1 = acc[mt][nt][1] + bb[1];
                float v2 = acc[mt][nt][2] + bb[2];
                float v3 = acc[mt][nt][3] + bb[3];
                h4.x = f32_bf16_rne(v0); l4.x = f32_bf16_rne(v0 - bf16_f32(h4.x));
                h4.y = f32_bf16_rne(v1); l4.y = f32_bf16_rne(v1 - bf16_f32(h4.y));
                h4.z = f32_bf16_rne(v2); l4.z = f32_bf16_rne(v2 - bf16_f32(h4.z));
                h4.w = f32_bf16_rne(v3); l4.w = f32_bf16_rne(v3 - bf16_f32(h4.w));
                *(ushort4*)(phi + off) = h4;
                *(ushort4*)(plo + off) = l4;
            }
        }
    } else {
        // V planes: tiles [c][t&63] -> per-element ushort stores (transposed)
        #pragma unroll
        for (int mt = 0; mt < 4; ++mt) {
            const int mv = m0 + wm + mt * 16 + quad * 4;
            const int head = mv >> 6;
            float bb[4];
            #pragma unroll
            for (int r = 0; r < 4; ++r) bb[r] = Bv[mv + r];
            #pragma unroll
            for (int nt = 0; nt < 2; ++nt) {
                const int t = n0 + wn + nt * 16 + l15;
                const int tile = t >> 6, jl = t & 63;
                const size_t tb = ((size_t)(b * Hn + head) * 16 + tile) << 12;
                #pragma unroll
                for (int r = 0; r < 4; ++r) {
                    const int cr = (mv & 63) + r;
                    const float v = acc[mt][nt][r] + bb[r];
                    const unsigned short h = f32_bf16_rne(v);
                    const size_t off = tb + sw(cr, jl);
                    vhi[off] = h;
                    vlo[off] = f32_bf16_rne(v - bf16_f32(h));
                }
            }
        }
    }
}

// ---------------------------------------------------------------------------
// MFMA flash attention. All operands arrive as pre-split, pre-swizzled bf16
// hi/lo tile planes -> staging is a pure uint4 copy. Q frags load straight
// from global (no Q LDS); rk = q·ek via 6 MFMAs + tiny LDS round-trip.
// LDS = 53760 B -> 2 blocks/CU. XCD-clustered decode: all 16 i-blocks of a
// (b,h) land on one XCD so its K/V planes (512 KB) live in that L2.
// ---------------------------------------------------------------------------
__global__ __launch_bounds__(256) void attn_mfma(
    const unsigned short* __restrict__ qhi, const unsigned short* __restrict__ qlo,
    const unsigned short* __restrict__ khi, const unsigned short* __restrict__ klo,
    const unsigned short* __restrict__ vhi, const unsigned short* __restrict__ vlo,
    const float* __restrict__ ek,   // [9,64]
    const float* __restrict__ ev,   // [9,64]
    float* __restrict__ ctx)        // [B,C,T]
{
    __shared__ alignas(16) unsigned short ksh[4096], ksl[4096];
    __shared__ alignas(16) unsigned short vsh[4096], vsl[4096];
    __shared__ alignas(16) unsigned short psh[4096], psl[4096];
    __shared__ float rk[576];       // [m][e], stride 9
    __shared__ float evs[576];      // [e][c]

    const int tid = threadIdx.x;

    // ---- XCD-clustered decode: 512 blocks, 64/XCD = 4 (b,h) x 16 i-tiles ----
    int it, h, b;
    {
        const int n = blockIdx.x;
        const int xcd = n & 7, slot = n >> 3;       // slot 0..63
        const int pair = (xcd << 2) | (slot >> 4);  // 0..31 = (b,h)
        it = slot & 15;
        b = pair >> 3;
        h = pair & 7;
    }
    const int i0 = it * 64;
    const int lane = tid & 63, w = tid >> 6;
    const int l15 = lane & 15, quad = lane >> 4;
    const int m_blk = w * 16 + l15;

    const size_t bh16 = (size_t)(b * Hn + h) * 16;
    float* ctxb = ctx + ((size_t)b * Cdim + h * KCd) * Tdim;

    // ---- Q frags straight from global (one-time) ----
    bf16x8 qfh[2], qfl[2];
    {
        const unsigned short* qth = qhi + ((bh16 + it) << 12);
        const unsigned short* qtl = qlo + ((bh16 + it) << 12);
        #pragma unroll
        for (int ks = 0; ks < 2; ++ks) {
            const int off = (m_blk << 6) + ((((ks << 2) | quad) ^ (m_blk & 7)) << 3);
            qfh[ks] = *(const bf16x8*)(qth + off);
            qfl[ks] = *(const bf16x8*)(qtl + off);
        }
    }

    // ---- ek B-frags in registers (lanes l15>=9 zero) ----
    bf16x8 ekh[2], ekl[2];
    #pragma unroll
    for (int ks = 0; ks < 2; ++ks) {
        #pragma unroll
        for (int j = 0; j < 8; ++j) { ekh[ks][j] = 0; ekl[ks][j] = 0; }
        if (l15 < 9) {
            #pragma unroll
            for (int j = 0; j < 8; ++j) {
                const float v = ek[l15 * 64 + ks * 32 + quad * 8 + j];
                const unsigned short hh = f32_bf16_rne(v);
                ekh[ks][j] = (short)hh;
                ekl[ks][j] = (short)f32_bf16_rne(v - bf16_f32(hh));
            }
        }
    }

    // ---- rk[m][e] = q[m]·ek[e] via MFMA (raw, pre-scale) ----
    {
        f32x4 rkD = (f32x4){0.f, 0.f, 0.f, 0.f};
        #pragma unroll
        for (int ks = 0; ks < 2; ++ks) {
            rkD = __builtin_amdgcn_mfma_f32_16x16x32_bf16(qfh[ks], ekh[ks], rkD, 0, 0, 0);
            rkD = __builtin_amdgcn_mfma_f32_16x16x32_bf16(qfh[ks], ekl[ks], rkD, 0, 0, 0);
            rkD = __builtin_amdgcn_mfma_f32_16x16x32_bf16(qfl[ks], ekh[ks], rkD, 0, 0, 0);
        }
        if (l15 < 9) {
            #pragma unroll
            for (int r = 0; r < 4; ++r)
                rk[(w * 16 + quad * 4 + r) * 9 + l15] = rkD[r];
        }
    }
    for (int idx = tid; idx < 576; idx += 256) evs[idx] = ev[idx];

    float m_run = -1e30f, l_run = 0.f;
    f32x4 Oc[4];
    #pragma unroll
    for (int ct = 0; ct < 4; ++ct) Oc[ct] = (f32x4){0.f, 0.f, 0.f, 0.f};

    // ---- prefetch tile 0 (pure copies) ----
    const unsigned short* kh0 = khi + (bh16 << 12);
    const unsigned short* kl0 = klo + (bh16 << 12);
    const unsigned short* vh0 = vhi + (bh16 << 12);
    const unsigned short* vl0 = vlo + (bh16 << 12);
    uint4 kp[4], vp[4];
    kp[0] = *(const uint4*)(kh0 + tid * 8);
    kp[1] = *(const uint4*)(kh0 + (tid + 256) * 8);
    kp[2] = *(const uint4*)(kl0 + tid * 8);
    kp[3] = *(const uint4*)(kl0 + (tid + 256) * 8);
    vp[0] = *(const uint4*)(vh0 + tid * 8);
    vp[1] = *(const uint4*)(vh0 + (tid + 256) * 8);
    vp[2] = *(const uint4*)(vl0 + tid * 8);
    vp[3] = *(const uint4*)(vl0 + (tid + 256) * 8);

    for (int t = 0; t < 16; ++t) {
        const int j0 = t << 6;
        __syncthreads();   // prev GEMM2/rel-v LDS reads done (t=0: rk/evs writes)
        *(uint4*)&ksh[tid * 8] = kp[0];
        *(uint4*)&ksh[(tid + 256) * 8] = kp[1];
        *(uint4*)&ksl[tid * 8] = kp[2];
        *(uint4*)&ksl[(tid + 256) * 8] = kp[3];
        *(uint4*)&vsh[tid * 8] = vp[0];
        *(uint4*)&vsh[(tid + 256) * 8] = vp[1];
        *(uint4*)&vsl[tid * 8] = vp[2];
        *(uint4*)&vsl[(tid + 256) * 8] = vp[3];
        __syncthreads();   // K/V tile visible

        if (t < 15) {
            const size_t tb = (size_t)(t + 1) << 12;
            kp[0] = *(const uint4*)(kh0 + tb + tid * 8);
            kp[1] = *(const uint4*)(kh0 + tb + (tid + 256) * 8);
            kp[2] = *(const uint4*)(kl0 + tb + tid * 8);
            kp[3] = *(const uint4*)(kl0 + tb + (tid + 256) * 8);
            vp[0] = *(const uint4*)(vh0 + tb + tid * 8);
            vp[1] = *(const uint4*)(vh0 + tb + (tid + 256) * 8);
            vp[2] = *(const uint4*)(vl0 + tb + tid * 8);
            vp[3] = *(const uint4*)(vl0 + tb + (tid + 256) * 8);
        }

        // ---- GEMM1: S^T[j][m] (lane col = m_blk, rows j) ----
        f32x4 Sc[4];
        #pragma unroll
        for (int jt = 0; jt < 4; ++jt) Sc[jt] = (f32x4){0.f, 0.f, 0.f, 0.f};
        #pragma unroll
        for (int ks = 0; ks < 2; ++ks) {
            #pragma unroll
            for (int jt = 0; jt < 4; ++jt) {
                bf16x8 ah = fragld(ksh, jt * 16 + l15, ks, quad);
                bf16x8 al = fragld(ksl, jt * 16 + l15, ks, quad);
                Sc[jt] = __builtin_amdgcn_mfma_f32_16x16x32_bf16(ah, qfh[ks], Sc[jt], 0, 0, 0);
                Sc[jt] = __builtin_amdgcn_mfma_f32_16x16x32_bf16(ah, qfl[ks], Sc[jt], 0, 0, 0);
                Sc[jt] = __builtin_amdgcn_mfma_f32_16x16x32_bf16(al, qfh[ks], Sc[jt], 0, 0, 0);
            }
        }

        const int dt = j0 - i0;
        const bool diag = (dt >= -67 && dt <= 67);
        if (diag) {
            #pragma unroll
            for (int jt = 0; jt < 4; ++jt) {
                const int db = dt + jt * 16 + quad * 4 - m_blk;
                #pragma unroll
                for (int r = 0; r < 4; ++r) {
                    const int d = db + r;
                    if ((unsigned)(d + 4) <= 8u) Sc[jt][r] += rk[m_blk * 9 + d + 4];
                }
            }
        }

        // ---- scale + online softmax (per-lane row m_blk) ----
        float mt = -1e30f;
        #pragma unroll
        for (int jt = 0; jt < 4; ++jt)
            #pragma unroll
            for (int r = 0; r < 4; ++r) {
                Sc[jt][r] *= 0.125f;
                mt = fmaxf(mt, Sc[jt][r]);
            }
        mt = fmaxf(mt, __shfl_xor(mt, 16));
        mt = fmaxf(mt, __shfl_xor(mt, 32));
        const float mn = fmaxf(m_run, mt);
        const float alpha = __expf(m_run - mn);
        float rs = 0.f;
        #pragma unroll
        for (int jt = 0; jt < 4; ++jt)
            #pragma unroll
            for (int r = 0; r < 4; ++r) {
                const float e = __expf(Sc[jt][r] - mn);
                Sc[jt][r] = e;
                rs += e;
            }
        rs += __shfl_xor(rs, 16);
        rs += __shfl_xor(rs, 32);
        l_run = l_run * alpha + rs;
        m_run = mn;

        // ---- write P (A-layout [m][j], hi/lo) ----
        #pragma unroll
        for (int jt = 0; jt < 4; ++jt) {
            ushort4 ph, pl;
            ph.x = f32_bf16_rne(Sc[jt][0]); pl.x = f32_bf16_rne(Sc[jt][0] - bf16_f32(ph.x));
            ph.y = f32_bf16_rne(Sc[jt][1]); pl.y = f32_bf16_rne(Sc[jt][1] - bf16_f32(ph.y));
            ph.z = f32_bf16_rne(Sc[jt][2]); pl.z = f32_bf16_rne(Sc[jt][2] - bf16_f32(ph.z));
            ph.w = f32_bf16_rne(Sc[jt][3]); pl.w = f32_bf16_rne(Sc[jt][3] - bf16_f32(ph.w));
            const int o = sw(m_blk, jt * 16 + quad * 4);
            *(ushort4*)&psh[o] = ph;
            *(ushort4*)&psl[o] = pl;
        }
        __syncthreads();   // P visible

        // ---- GEMM2: O[m][c] += P·V, alpha-rescale first ----
        const float al0 = __shfl(alpha, quad * 4 + 0);
        const float al1 = __shfl(alpha, quad * 4 + 1);
        const float al2 = __shfl(alpha, quad * 4 + 2);
        const float al3 = __shfl(alpha, quad * 4 + 3);
        #pragma unroll
        for (int ct = 0; ct < 4; ++ct) {
            Oc[ct][0] *= al0; Oc[ct][1] *= al1; Oc[ct][2] *= al2; Oc[ct][3] *= al3;
        }
        #pragma unroll
        for (int ks = 0; ks < 2; ++ks) {
            bf16x8 pah = fragld(psh, m_blk, ks, quad);
            bf16x8 pal = fragld(psl, m_blk, ks, quad);
            #pragma unroll
            for (int ct = 0; ct < 4; ++ct) {
                bf16x8 bh = fragld(vsh, ct * 16 + l15, ks, quad);
                bf16x8 bl = fragld(vsl, ct * 16 + l15, ks, quad);
                Oc[ct] = __builtin_amdgcn_mfma_f32_16x16x32_bf16(pah, bh, Oc[ct], 0, 0, 0);
                Oc[ct] = __builtin_amdgcn_mfma_f32_16x16x32_bf16(pah, bl, Oc[ct], 0, 0, 0);
                Oc[ct] = __builtin_amdgcn_mfma_f32_16x16x32_bf16(pal, bh, Oc[ct], 0, 0, 0);
            }
        }

        if (diag) {   // banded rel-v via P in LDS
            #pragma unroll
            for (int r = 0; r < 4; ++r) {
                const int mrow = w * 16 + quad * 4 + r;
                const int ig = i0 + mrow;
                #pragma unroll
                for (int e = 0; e < 9; ++e) {
                    const int jl = ig + e - 4 - j0;
                    if ((unsigned)jl < 64u) {
                        const int o = sw(mrow, jl);
                        const float p = bf16_f32(psh[o]) + bf16_f32(psl[o]);
                        #pragma unroll
                        for (int ct = 0; ct < 4; ++ct)
                            Oc[ct][r] += p * evs[e * 64 + ct * 16 + l15];
                    }
                }
            }
        }
    }

    // ---- epilogue: normalize rows, store ctx natural [B,C,T] ----
    const float rlv = 1.f / l_run;
    const float rl0 = __shfl(rlv, quad * 4 + 0);
    const float rl1 = __shfl(rlv, quad * 4 + 1);
    const float rl2 = __shfl(rlv, quad * 4 + 2);
    const float rl3 = __shfl(rlv, quad * 4 + 3);
    #pragma unroll
    for (int ct = 0; ct < 4; ++ct) {
        float4 o4;
        o4.x = Oc[ct][0] * rl0;
        o4.y = Oc[ct][1] * rl1;
        o4.z = Oc[ct][2] * rl2;
        o4.w = Oc[ct][3] * rl3;
        *(float4*)(ctxb + (size_t)(ct * 16 + l15) * Tdim + i0 + w * 16 + quad * 4) = o4;
    }
}

// ---------------------------------------------------------------------------
extern "C" void kernel_launch(void* const* d_in, const int* in_sizes, int n_in,
                              void* d_out, int out_size, void* d_ws, size_t ws_size,
                              hipStream_t stream) {
    const float* x  = (const float*)d_in[0];
    const float* wq = (const float*)d_in[1];
    const float* bq = (const float*)d_in[2];
    const float* wk = (const float*)d_in[3];
    const float* bk = (const float*)d_in[4];
    const float* wv = (const float*)d_in[5];
    const float* bv = (const float*)d_in[6];
    const float* wo = (const float*)d_in[7];
    const float* bo = (const float*)d_in[8];
    const float* ek = (const float*)d_in[9];
    const float* ev = (const float*)d_in[10];
    float* out = (float*)d_out;

    const size_t plane = (size_t)Bdim * Cdim * Tdim;  // 2M elements
    unsigned short* qhi = (unsigned short*)d_ws;
    unsigned short* qlo = qhi + plane;
    unsigned short* khi = qlo + plane;
    unsigned short* klo = khi + plane;
    unsigned short* vhi = klo + plane;
    unsigned short* vlo = vhi + plane;
    float* cbuf = (float*)(vlo + plane);              // 8 MB fp32

    // QKV projection -> pre-split, pre-swizzled bf16 tile planes
    gemm3_mfma<<<dim3(768), 256, 0, stream>>>(
        0, wq, wk, wv, bq, bk, bv, x, qhi, qlo, khi, klo, vhi, vlo, nullptr);

    // MFMA flash attention with banded relative terms
    attn_mfma<<<dim3(512), 256, 0, stream>>>(
        qhi, qlo, khi, klo, vhi, vlo, ek, ev, cbuf);

    // output projection (natural fp32 store)
    gemm3_mfma<<<dim3(256), 256, 0, stream>>>(
        1, wo, wo, wo, bo, bo, bo, cbuf,
        nullptr, nullptr, nullptr, nullptr, nullptr, nullptr, out);
}

// Round 7
// 224.418 us; speedup vs baseline: 1.0994x; 1.0644x over previous
//
#include <hip/hip_runtime.h>
#include <hip/hip_bf16.h>

// Problem constants (B, C, T, H, KC, WIN) = (4, 512, 1024, 8, 64, 4)
#define Bdim 4
#define Cdim 512
#define Tdim 1024
#define Hn   8
#define KCd  64

typedef __attribute__((ext_vector_type(8))) short bf16x8;   // 8 bf16 = 4 VGPR
typedef __attribute__((ext_vector_type(4))) float f32x4;    // MFMA C/D

__device__ __forceinline__ unsigned short f32_bf16_rne(float f) {
    unsigned u = __float_as_uint(f);
    u += 0x7FFFu + ((u >> 16) & 1u);
    return (unsigned short)(u >> 16);
}
__device__ __forceinline__ float bf16_f32(unsigned short h) {
    return __uint_as_float(((unsigned)h) << 16);
}

// 64x64 bf16 tile, 16B-chunk XOR swizzle (row stride 128 B, chunk ^= row&7).
// Same image in global planes and in LDS -> frags load identically from both.
__device__ __forceinline__ int sw(int row, int col) {
    return (row << 6) + ((((col >> 3) ^ (row & 7)) << 3) | (col & 7));
}
__device__ __forceinline__ bf16x8 fragld(const unsigned short* a, int row, int kstep, int quad) {
    return *(const bf16x8*)&a[(row << 6) + ((((kstep << 2) | quad) ^ (row & 7)) << 3)];
}

// ---------------------------------------------------------------------------
// bf16x3 MFMA GEMM: out[b,m,n] = sum_k W[m,k] * X[b,k,n] + bias[m]
// mode 0 (QKV): sel 0 (Q) and sel 1 (K) -> bf16 hi/lo planes, tiles [t][c];
//               sel 2 (V) -> bf16 hi/lo planes, tiles [c][t]. All swizzled.
// mode 1 (out-proj): natural fp32 [B,C,T] store.
// XCD-clustered decode (id%8 -> XCD round-robin heuristic).
// ---------------------------------------------------------------------------
#define BM 128
#define BN 64
#define BK 32
#define LDK 40

__global__ __launch_bounds__(256) void gemm3_mfma(
    int mode,
    const float* __restrict__ w0, const float* __restrict__ w1, const float* __restrict__ w2,
    const float* __restrict__ b0, const float* __restrict__ b1, const float* __restrict__ b2,
    const float* __restrict__ x,
    unsigned short* __restrict__ qhi, unsigned short* __restrict__ qlo,
    unsigned short* __restrict__ khi, unsigned short* __restrict__ klo,
    unsigned short* __restrict__ vhi, unsigned short* __restrict__ vlo,
    float* __restrict__ ofp)
{
    __shared__ unsigned short Whi[BM][LDK], Wlo[BM][LDK];
    __shared__ unsigned short Xhi[BN][LDK], Xlo[BN][LDK];

    const int tid = threadIdx.x;

    // ---- XCD-clustered decode ----
    int bx, by, b;
    {
        const int n = blockIdx.x;
        const int xcd = n & 7, slot = n >> 3;
        if (mode == 0) {
            const int stripe = (xcd << 3) | (slot / 12);   // 0..63 = (b,bx)
            by = slot % 12;
            bx = stripe & 15;
            b  = stripe >> 4;
        } else {
            const int stripe = (xcd << 3) | (slot >> 2);
            by = slot & 3;
            bx = stripe & 15;
            b  = stripe >> 4;
        }
    }

    const int m_tile = by * BM;
    const int sel = m_tile >> 9;
    const float* W  = sel == 0 ? w0 : (sel == 1 ? w1 : w2);
    const float* Bv = sel == 0 ? b0 : (sel == 1 ? b1 : b2);
    const int m0 = m_tile & 511;
    const int n0 = bx * BN;

    const float* Xb = x + (size_t)b * Cdim * Tdim;

    const int lane = tid & 63, wid = tid >> 6;
    const int wm = (wid & 1) * 64, wn = (wid >> 1) * 32;
    const int l15 = lane & 15, quad = lane >> 4;

    const int wk4 = (tid & 7) * 4;
    const int wmr = tid >> 3;
    const int xn  = tid & 63;
    const int xo  = tid >> 6;

    f32x4 acc[4][2];
    #pragma unroll
    for (int i = 0; i < 4; ++i)
        #pragma unroll
        for (int j = 0; j < 2; ++j) acc[i][j] = (f32x4){0.f, 0.f, 0.f, 0.f};

    for (int k0 = 0; k0 < Cdim; k0 += BK) {
        __syncthreads();

        #pragma unroll
        for (int p = 0; p < 4; ++p) {
            const int m = wmr + p * 32;
            float4 wv = *(const float4*)(W + (size_t)(m0 + m) * Cdim + k0 + wk4);
            ushort4 hi, lo;
            hi.x = f32_bf16_rne(wv.x); lo.x = f32_bf16_rne(wv.x - bf16_f32(hi.x));
            hi.y = f32_bf16_rne(wv.y); lo.y = f32_bf16_rne(wv.y - bf16_f32(hi.y));
            hi.z = f32_bf16_rne(wv.z); lo.z = f32_bf16_rne(wv.z - bf16_f32(hi.z));
            hi.w = f32_bf16_rne(wv.w); lo.w = f32_bf16_rne(wv.w - bf16_f32(hi.w));
            *(ushort4*)&Whi[m][wk4] = hi;
            *(ushort4*)&Wlo[m][wk4] = lo;
        }

        {
            float xv[8];
            #pragma unroll
            for (int kk = 0; kk < 8; ++kk)
                xv[kk] = Xb[(size_t)(k0 + xo * 8 + kk) * Tdim + n0 + xn];
            ushort4 hi0, hi1, lo0, lo1;
            unsigned short h;
            h = f32_bf16_rne(xv[0]); hi0.x = h; lo0.x = f32_bf16_rne(xv[0] - bf16_f32(h));
            h = f32_bf16_rne(xv[1]); hi0.y = h; lo0.y = f32_bf16_rne(xv[1] - bf16_f32(h));
            h = f32_bf16_rne(xv[2]); hi0.z = h; lo0.z = f32_bf16_rne(xv[2] - bf16_f32(h));
            h = f32_bf16_rne(xv[3]); hi0.w = h; lo0.w = f32_bf16_rne(xv[3] - bf16_f32(h));
            h = f32_bf16_rne(xv[4]); hi1.x = h; lo1.x = f32_bf16_rne(xv[4] - bf16_f32(h));
            h = f32_bf16_rne(xv[5]); hi1.y = h; lo1.y = f32_bf16_rne(xv[5] - bf16_f32(h));
            h = f32_bf16_rne(xv[6]); hi1.z = h; lo1.z = f32_bf16_rne(xv[6] - bf16_f32(h));
            h = f32_bf16_rne(xv[7]); hi1.w = h; lo1.w = f32_bf16_rne(xv[7] - bf16_f32(h));
            *(ushort4*)&Xhi[xn][xo * 8]     = hi0;
            *(ushort4*)&Xhi[xn][xo * 8 + 4] = hi1;
            *(ushort4*)&Xlo[xn][xo * 8]     = lo0;
            *(ushort4*)&Xlo[xn][xo * 8 + 4] = lo1;
        }
        __syncthreads();

        bf16x8 ahi[4], alo[4], bhi[2], blo[2];
        #pragma unroll
        for (int mt = 0; mt < 4; ++mt) {
            ahi[mt] = *(const bf16x8*)&Whi[wm + mt * 16 + l15][quad * 8];
            alo[mt] = *(const bf16x8*)&Wlo[wm + mt * 16 + l15][quad * 8];
        }
        #pragma unroll
        for (int nt = 0; nt < 2; ++nt) {
            bhi[nt] = *(const bf16x8*)&Xhi[wn + nt * 16 + l15][quad * 8];
            blo[nt] = *(const bf16x8*)&Xlo[wn + nt * 16 + l15][quad * 8];
        }
        #pragma unroll
        for (int mt = 0; mt < 4; ++mt)
            #pragma unroll
            for (int nt = 0; nt < 2; ++nt) {
                f32x4 c = acc[mt][nt];
                c = __builtin_amdgcn_mfma_f32_16x16x32_bf16(ahi[mt], bhi[nt], c, 0, 0, 0);
                c = __builtin_amdgcn_mfma_f32_16x16x32_bf16(ahi[mt], blo[nt], c, 0, 0, 0);
                c = __builtin_amdgcn_mfma_f32_16x16x32_bf16(alo[mt], bhi[nt], c, 0, 0, 0);
                acc[mt][nt] = c;
            }
    }

    // ---- epilogue ----
    if (mode == 1) {
        float* Ob = ofp + (size_t)b * Cdim * Tdim;
        #pragma unroll
        for (int mt = 0; mt < 4; ++mt) {
            const int mb = m0 + wm + mt * 16 + quad * 4;
            float bb[4];
            #pragma unroll
            for (int r = 0; r < 4; ++r) bb[r] = Bv[mb + r];
            #pragma unroll
            for (int nt = 0; nt < 2; ++nt) {
                const int t = n0 + wn + nt * 16 + l15;
                #pragma unroll
                for (int r = 0; r < 4; ++r)
                    Ob[(size_t)(mb + r) * Tdim + t] = acc[mt][nt][r] + bb[r];
            }
        }
    } else if (sel < 2) {
        // Q/K planes: tiles [t&63][c], ushort4 along c
        unsigned short* phi = sel == 0 ? qhi : khi;
        unsigned short* plo = sel == 0 ? qlo : klo;
        #pragma unroll
        for (int mt = 0; mt < 4; ++mt) {
            const int mv = m0 + wm + mt * 16 + quad * 4;
            const int head = mv >> 6, c0 = mv & 63;
            float bb[4];
            #pragma unroll
            for (int r = 0; r < 4; ++r) bb[r] = Bv[mv + r];
            #pragma unroll
            for (int nt = 0; nt < 2; ++nt) {
                const int t = n0 + wn + nt * 16 + l15;
                const int tile = t >> 6, r_ = t & 63;
                const size_t off = (((size_t)(b * Hn + head) * 16 + tile) << 12)
                                 + (size_t)sw(r_, c0);
                ushort4 h4, l4;
                float v0 = acc[mt][nt][0] + bb[0];
                float v1 = acc[mt][nt][1] + bb[1];
                float v2 = acc[mt][nt][2] + bb[2];
                float v3 = acc[mt][nt][3] + bb[3];
                h4.x = f32_bf16_rne(v0); l4.x = f32_bf16_rne(v0 - bf16_f32(h4.x));
                h4.y = f32_bf16_rne(v1); l4.y = f32_bf16_rne(v1 - bf16_f32(h4.y));
                h4.z = f32_bf16_rne(v2); l4.z = f32_bf16_rne(v2 - bf16_f32(h4.z));
                h4.w = f32_bf16_rne(v3); l4.w = f32_bf16_rne(v3 - bf16_f32(h4.w));
                *(ushort4*)(phi + off) = h4;
                *(ushort4*)(plo + off) = l4;
            }
        }
    } else {
        // V planes: tiles [c][t&63] -> per-element ushort stores (transposed)
        #pragma unroll
        for (int mt = 0; mt < 4; ++mt) {
            const int mv = m0 + wm + mt * 16 + quad * 4;
            const int head = mv >> 6;
            float bb[4];
            #pragma unroll
            for (int r = 0; r < 4; ++r) bb[r] = Bv[mv + r];
            #pragma unroll
            for (int nt = 0; nt < 2; ++nt) {
                const int t = n0 + wn + nt * 16 + l15;
                const int tile = t >> 6, jl = t & 63;
                const size_t tb = ((size_t)(b * Hn + head) * 16 + tile) << 12;
                #pragma unroll
                for (int r = 0; r < 4; ++r) {
                    const int cr = (mv & 63) + r;
                    const float v = acc[mt][nt][r] + bb[r];
                    const unsigned short h = f32_bf16_rne(v);
                    const size_t off = tb + sw(cr, jl);
                    vhi[off] = h;
                    vlo[off] = f32_bf16_rne(v - bf16_f32(h));
                }
            }
        }
    }
}

// ---------------------------------------------------------------------------
// Barrier-free MFMA flash attention. K/V/Q frags load DIRECTLY from the
// pre-swizzled global planes (no LDS staging, no staging barriers). P's LDS
// round-trip is intra-wave only (wave w writes/reads rows [16w,16w+16)), so
// compiler lgkmcnt ordering suffices -> zero barriers in the j-loop.
// LDS ~21 KB. Grid 512 = 2 blocks/CU, 8 independent self-paced waves/CU.
// ---------------------------------------------------------------------------
__global__ __launch_bounds__(256) void attn_mfma(
    const unsigned short* __restrict__ qhi, const unsigned short* __restrict__ qlo,
    const unsigned short* __restrict__ khi, const unsigned short* __restrict__ klo,
    const unsigned short* __restrict__ vhi, const unsigned short* __restrict__ vlo,
    const float* __restrict__ ek,   // [9,64]
    const float* __restrict__ ev,   // [9,64]
    float* __restrict__ ctx)        // [B,C,T]
{
    __shared__ alignas(16) unsigned short psh[4096], psl[4096];
    __shared__ float rk[576];       // [m][e], stride 9
    __shared__ float evs[576];      // [e][c]

    const int tid = threadIdx.x;

    // ---- XCD-clustered decode: 512 blocks, 64/XCD = 4 (b,h) x 16 i-tiles ----
    int it, h, b;
    {
        const int n = blockIdx.x;
        const int xcd = n & 7, slot = n >> 3;
        const int pair = (xcd << 2) | (slot >> 4);
        it = slot & 15;
        b = pair >> 3;
        h = pair & 7;
    }
    const int i0 = it * 64;
    const int lane = tid & 63, w = tid >> 6;
    const int l15 = lane & 15, quad = lane >> 4;
    const int m_blk = w * 16 + l15;

    const size_t bh16 = (size_t)(b * Hn + h) * 16;
    float* ctxb = ctx + ((size_t)b * Cdim + h * KCd) * Tdim;

    // ---- Q frags straight from global (one-time) ----
    bf16x8 qfh[2], qfl[2];
    {
        const unsigned short* qth = qhi + ((bh16 + it) << 12);
        const unsigned short* qtl = qlo + ((bh16 + it) << 12);
        #pragma unroll
        for (int ks = 0; ks < 2; ++ks) {
            qfh[ks] = fragld(qth, m_blk, ks, quad);
            qfl[ks] = fragld(qtl, m_blk, ks, quad);
        }
    }

    // ---- ek B-frags in registers (lanes l15>=9 zero) ----
    bf16x8 ekh[2], ekl[2];
    #pragma unroll
    for (int ks = 0; ks < 2; ++ks) {
        #pragma unroll
        for (int j = 0; j < 8; ++j) { ekh[ks][j] = 0; ekl[ks][j] = 0; }
        if (l15 < 9) {
            #pragma unroll
            for (int j = 0; j < 8; ++j) {
                const float v = ek[l15 * 64 + ks * 32 + quad * 8 + j];
                const unsigned short hh = f32_bf16_rne(v);
                ekh[ks][j] = (short)hh;
                ekl[ks][j] = (short)f32_bf16_rne(v - bf16_f32(hh));
            }
        }
    }

    // ---- rk[m][e] = q[m]·ek[e] via MFMA (raw, pre-scale) ----
    {
        f32x4 rkD = (f32x4){0.f, 0.f, 0.f, 0.f};
        #pragma unroll
        for (int ks = 0; ks < 2; ++ks) {
            rkD = __builtin_amdgcn_mfma_f32_16x16x32_bf16(qfh[ks], ekh[ks], rkD, 0, 0, 0);
            rkD = __builtin_amdgcn_mfma_f32_16x16x32_bf16(qfh[ks], ekl[ks], rkD, 0, 0, 0);
            rkD = __builtin_amdgcn_mfma_f32_16x16x32_bf16(qfl[ks], ekh[ks], rkD, 0, 0, 0);
        }
        if (l15 < 9) {
            #pragma unroll
            for (int r = 0; r < 4; ++r)
                rk[(w * 16 + quad * 4 + r) * 9 + l15] = rkD[r];
        }
    }
    for (int idx = tid; idx < 576; idx += 256) evs[idx] = ev[idx];
    __syncthreads();   // the ONLY barrier: evs (cross-wave) visible

    float m_run = -1e30f, l_run = 0.f;
    f32x4 Oc[4];
    #pragma unroll
    for (int ct = 0; ct < 4; ++ct) Oc[ct] = (f32x4){0.f, 0.f, 0.f, 0.f};

    const unsigned short* kh0 = khi + (bh16 << 12);
    const unsigned short* kl0 = klo + (bh16 << 12);
    const unsigned short* vh0 = vhi + (bh16 << 12);
    const unsigned short* vl0 = vlo + (bh16 << 12);

    for (int t = 0; t < 16; ++t) {
        const int j0 = t << 6;
        const size_t tb = (size_t)t << 12;
        const unsigned short* kht = kh0 + tb;
        const unsigned short* klt = kl0 + tb;
        const unsigned short* vht = vh0 + tb;
        const unsigned short* vlt = vl0 + tb;

        // ---- GEMM1: S^T[j][m], K frags direct from global ----
        f32x4 Sc[4];
        #pragma unroll
        for (int jt = 0; jt < 4; ++jt) Sc[jt] = (f32x4){0.f, 0.f, 0.f, 0.f};
        #pragma unroll
        for (int ks = 0; ks < 2; ++ks) {
            bf16x8 ah[4], al[4];
            #pragma unroll
            for (int jt = 0; jt < 4; ++jt) {
                ah[jt] = fragld(kht, jt * 16 + l15, ks, quad);
                al[jt] = fragld(klt, jt * 16 + l15, ks, quad);
            }
            #pragma unroll
            for (int jt = 0; jt < 4; ++jt) {
                Sc[jt] = __builtin_amdgcn_mfma_f32_16x16x32_bf16(ah[jt], qfh[ks], Sc[jt], 0, 0, 0);
                Sc[jt] = __builtin_amdgcn_mfma_f32_16x16x32_bf16(ah[jt], qfl[ks], Sc[jt], 0, 0, 0);
                Sc[jt] = __builtin_amdgcn_mfma_f32_16x16x32_bf16(al[jt], qfh[ks], Sc[jt], 0, 0, 0);
            }
        }

        const int dt = j0 - i0;
        const bool diag = (dt >= -67 && dt <= 67);
        if (diag) {
            #pragma unroll
            for (int jt = 0; jt < 4; ++jt) {
                const int db = dt + jt * 16 + quad * 4 - m_blk;
                #pragma unroll
                for (int r = 0; r < 4; ++r) {
                    const int d = db + r;
                    if ((unsigned)(d + 4) <= 8u) Sc[jt][r] += rk[m_blk * 9 + d + 4];
                }
            }
        }

        // ---- scale + online softmax (per-lane row m_blk) ----
        float mt = -1e30f;
        #pragma unroll
        for (int jt = 0; jt < 4; ++jt)
            #pragma unroll
            for (int r = 0; r < 4; ++r) {
                Sc[jt][r] *= 0.125f;
                mt = fmaxf(mt, Sc[jt][r]);
            }
        mt = fmaxf(mt, __shfl_xor(mt, 16));
        mt = fmaxf(mt, __shfl_xor(mt, 32));
        const float mn = fmaxf(m_run, mt);
        const float alpha = __expf(m_run - mn);
        float rs = 0.f;
        #pragma unroll
        for (int jt = 0; jt < 4; ++jt)
            #pragma unroll
            for (int r = 0; r < 4; ++r) {
                const float e = __expf(Sc[jt][r] - mn);
                Sc[jt][r] = e;
                rs += e;
            }
        rs += __shfl_xor(rs, 16);
        rs += __shfl_xor(rs, 32);
        l_run = l_run * alpha + rs;
        m_run = mn;

        // ---- write P (A-layout [m][j], hi/lo); intra-wave rows only ----
        #pragma unroll
        for (int jt = 0; jt < 4; ++jt) {
            ushort4 ph, pl;
            ph.x = f32_bf16_rne(Sc[jt][0]); pl.x = f32_bf16_rne(Sc[jt][0] - bf16_f32(ph.x));
            ph.y = f32_bf16_rne(Sc[jt][1]); pl.y = f32_bf16_rne(Sc[jt][1] - bf16_f32(ph.y));
            ph.z = f32_bf16_rne(Sc[jt][2]); pl.z = f32_bf16_rne(Sc[jt][2] - bf16_f32(ph.z));
            ph.w = f32_bf16_rne(Sc[jt][3]); pl.w = f32_bf16_rne(Sc[jt][3] - bf16_f32(ph.w));
            const int o = sw(m_blk, jt * 16 + quad * 4);
            *(ushort4*)&psh[o] = ph;
            *(ushort4*)&psl[o] = pl;
        }
        // no barrier: wave w reads only rows [16w,16w+16) which it just wrote

        // ---- GEMM2: O[m][c] += P·V, V frags direct from global ----
        const float al0 = __shfl(alpha, quad * 4 + 0);
        const float al1 = __shfl(alpha, quad * 4 + 1);
        const float al2 = __shfl(alpha, quad * 4 + 2);
        const float al3 = __shfl(alpha, quad * 4 + 3);
        #pragma unroll
        for (int ct = 0; ct < 4; ++ct) {
            Oc[ct][0] *= al0; Oc[ct][1] *= al1; Oc[ct][2] *= al2; Oc[ct][3] *= al3;
        }
        #pragma unroll
        for (int ks = 0; ks < 2; ++ks) {
            bf16x8 bh[4], bl[4];
            #pragma unroll
            for (int ct = 0; ct < 4; ++ct) {
                bh[ct] = fragld(vht, ct * 16 + l15, ks, quad);
                bl[ct] = fragld(vlt, ct * 16 + l15, ks, quad);
            }
            bf16x8 pah = fragld(psh, m_blk, ks, quad);
            bf16x8 pal = fragld(psl, m_blk, ks, quad);
            #pragma unroll
            for (int ct = 0; ct < 4; ++ct) {
                Oc[ct] = __builtin_amdgcn_mfma_f32_16x16x32_bf16(pah, bh[ct], Oc[ct], 0, 0, 0);
                Oc[ct] = __builtin_amdgcn_mfma_f32_16x16x32_bf16(pah, bl[ct], Oc[ct], 0, 0, 0);
                Oc[ct] = __builtin_amdgcn_mfma_f32_16x16x32_bf16(pal, bh[ct], Oc[ct], 0, 0, 0);
            }
        }

        if (diag) {   // banded rel-v via P in LDS (own wave's rows)
            #pragma unroll
            for (int r = 0; r < 4; ++r) {
                const int mrow = w * 16 + quad * 4 + r;
                const int ig = i0 + mrow;
                #pragma unroll
                for (int e = 0; e < 9; ++e) {
                    const int jl = ig + e - 4 - j0;
                    if ((unsigned)jl < 64u) {
                        const int o = sw(mrow, jl);
                        const float p = bf16_f32(psh[o]) + bf16_f32(psl[o]);
                        #pragma unroll
                        for (int ct = 0; ct < 4; ++ct)
                            Oc[ct][r] += p * evs[e * 64 + ct * 16 + l15];
                    }
                }
            }
        }
    }

    // ---- epilogue: normalize rows, store ctx natural [B,C,T] ----
    const float rlv = 1.f / l_run;
    const float rl0 = __shfl(rlv, quad * 4 + 0);
    const float rl1 = __shfl(rlv, quad * 4 + 1);
    const float rl2 = __shfl(rlv, quad * 4 + 2);
    const float rl3 = __shfl(rlv, quad * 4 + 3);
    #pragma unroll
    for (int ct = 0; ct < 4; ++ct) {
        float4 o4;
        o4.x = Oc[ct][0] * rl0;
        o4.y = Oc[ct][1] * rl1;
        o4.z = Oc[ct][2] * rl2;
        o4.w = Oc[ct][3] * rl3;
        *(float4*)(ctxb + (size_t)(ct * 16 + l15) * Tdim + i0 + w * 16 + quad * 4) = o4;
    }
}

// ---------------------------------------------------------------------------
extern "C" void kernel_launch(void* const* d_in, const int* in_sizes, int n_in,
                              void* d_out, int out_size, void* d_ws, size_t ws_size,
                              hipStream_t stream) {
    const float* x  = (const float*)d_in[0];
    const float* wq = (const float*)d_in[1];
    const float* bq = (const float*)d_in[2];
    const float* wk = (const float*)d_in[3];
    const float* bk = (const float*)d_in[4];
    const float* wv = (const float*)d_in[5];
    const float* bv = (const float*)d_in[6];
    const float* wo = (const float*)d_in[7];
    const float* bo = (const float*)d_in[8];
    const float* ek = (const float*)d_in[9];
    const float* ev = (const float*)d_in[10];
    float* out = (float*)d_out;

    const size_t plane = (size_t)Bdim * Cdim * Tdim;  // 2M elements
    unsigned short* qhi = (unsigned short*)d_ws;
    unsigned short* qlo = qhi + plane;
    unsigned short* khi = qlo + plane;
    unsigned short* klo = khi + plane;
    unsigned short* vhi = klo + plane;
    unsigned short* vlo = vhi + plane;
    float* cbuf = (float*)(vlo + plane);              // 8 MB fp32

    // QKV projection -> pre-split, pre-swizzled bf16 tile planes
    gemm3_mfma<<<dim3(768), 256, 0, stream>>>(
        0, wq, wk, wv, bq, bk, bv, x, qhi, qlo, khi, klo, vhi, vlo, nullptr);

    // barrier-free MFMA flash attention with banded relative terms
    attn_mfma<<<dim3(512), 256, 0, stream>>>(
        qhi, qlo, khi, klo, vhi, vlo, ek, ev, cbuf);

    // output projection (natural fp32 store)
    gemm3_mfma<<<dim3(256), 256, 0, stream>>>(
        1, wo, wo, wo, bo, bo, bo, cbuf,
        nullptr, nullptr, nullptr, nullptr, nullptr, nullptr, out);
}

// Round 8
// 182.796 us; speedup vs baseline: 1.3498x; 1.2277x over previous
//
#include <hip/hip_runtime.h>
#include <hip/hip_bf16.h>

// Problem constants (B, C, T, H, KC, WIN) = (4, 512, 1024, 8, 64, 4)
#define Bdim 4
#define Cdim 512
#define Tdim 1024
#define Hn   8
#define KCd  64

typedef __attribute__((ext_vector_type(8))) short bf16x8;   // 8 bf16 = 4 VGPR
typedef __attribute__((ext_vector_type(4))) float f32x4;    // MFMA C/D

__device__ __forceinline__ unsigned short f32_bf16_rne(float f) {
    unsigned u = __float_as_uint(f);
    u += 0x7FFFu + ((u >> 16) & 1u);
    return (unsigned short)(u >> 16);
}
__device__ __forceinline__ float bf16_f32(unsigned short h) {
    return __uint_as_float(((unsigned)h) << 16);
}

// ---------------------------------------------------------------------------
// FRAG-MAJOR global tile layout (4096 ushorts per 64x64 tile):
//   tile = [g:8][lane:64][e:8],  g = (rowgrp)*2 + ks
// "row-type" planes (Q,K: row=time/m, col=c): element (row,c) at
//   g=(row>>4)*2+(c>>5), lane=((c>>3)&3)*16+(row&15), e=c&7
// "col-type" plane (V: row=c, col=j): element (c,j) at
//   g=(c>>4)*2+(j>>5),  lane=((j>>3)&3)*16+(c&15),  e=j&7
// A wave's MFMA fragment (g fixed) is the contiguous 1 KB [lane][e] -> every
// attention frag load is a single coalesced dwordx4 with invariant offset.
// ---------------------------------------------------------------------------
__device__ __forceinline__ int off_row(int row, int c) {
    return (((row >> 4) * 2 + (c >> 5)) << 9)
         + (((((c >> 3) & 3) << 4) + (row & 15)) << 3) + (c & 7);
}
__device__ __forceinline__ int off_col(int c, int j) {
    return (((c >> 4) * 2 + (j >> 5)) << 9)
         + (((((j >> 3) & 3) << 4) + (c & 15)) << 3) + (j & 7);
}

// LDS 64x64 tile XOR swizzle (used only for the P round-trip now)
__device__ __forceinline__ int sw(int row, int col) {
    return (row << 6) + ((((col >> 3) ^ (row & 7)) << 3) | (col & 7));
}
__device__ __forceinline__ bf16x8 fragld(const unsigned short* a, int row, int kstep, int quad) {
    return *(const bf16x8*)&a[(row << 6) + ((((kstep << 2) | quad) ^ (row & 7)) << 3)];
}

// ---------------------------------------------------------------------------
// bf16x3 MFMA GEMM: out[b,m,n] = sum_k W[m,k] * X[b,k,n] + bias[m]
// mode 0 (QKV): sel 0 (Q), sel 1 (K) -> frag-major row-type planes;
//               sel 2 (V) -> frag-major col-type planes.
// mode 1 (out-proj): natural fp32 [B,C,T] store.
// XCD-clustered decode (id%8 -> XCD round-robin heuristic).
// ---------------------------------------------------------------------------
#define BM 128
#define BN 64
#define BK 32
#define LDK 40

__global__ __launch_bounds__(256) void gemm3_mfma(
    int mode,
    const float* __restrict__ w0, const float* __restrict__ w1, const float* __restrict__ w2,
    const float* __restrict__ b0, const float* __restrict__ b1, const float* __restrict__ b2,
    const float* __restrict__ x,
    unsigned short* __restrict__ qhi, unsigned short* __restrict__ qlo,
    unsigned short* __restrict__ khi, unsigned short* __restrict__ klo,
    unsigned short* __restrict__ vhi, unsigned short* __restrict__ vlo,
    float* __restrict__ ofp)
{
    __shared__ unsigned short Whi[BM][LDK], Wlo[BM][LDK];
    __shared__ unsigned short Xhi[BN][LDK], Xlo[BN][LDK];

    const int tid = threadIdx.x;

    // ---- XCD-clustered decode ----
    int bx, by, b;
    {
        const int n = blockIdx.x;
        const int xcd = n & 7, slot = n >> 3;
        if (mode == 0) {
            const int stripe = (xcd << 3) | (slot / 12);   // 0..63 = (b,bx)
            by = slot % 12;
            bx = stripe & 15;
            b  = stripe >> 4;
        } else {
            const int stripe = (xcd << 3) | (slot >> 2);
            by = slot & 3;
            bx = stripe & 15;
            b  = stripe >> 4;
        }
    }

    const int m_tile = by * BM;
    const int sel = m_tile >> 9;
    const float* W  = sel == 0 ? w0 : (sel == 1 ? w1 : w2);
    const float* Bv = sel == 0 ? b0 : (sel == 1 ? b1 : b2);
    const int m0 = m_tile & 511;
    const int n0 = bx * BN;

    const float* Xb = x + (size_t)b * Cdim * Tdim;

    const int lane = tid & 63, wid = tid >> 6;
    const int wm = (wid & 1) * 64, wn = (wid >> 1) * 32;
    const int l15 = lane & 15, quad = lane >> 4;

    const int wk4 = (tid & 7) * 4;
    const int wmr = tid >> 3;
    const int xn  = tid & 63;
    const int xo  = tid >> 6;

    f32x4 acc[4][2];
    #pragma unroll
    for (int i = 0; i < 4; ++i)
        #pragma unroll
        for (int j = 0; j < 2; ++j) acc[i][j] = (f32x4){0.f, 0.f, 0.f, 0.f};

    for (int k0 = 0; k0 < Cdim; k0 += BK) {
        __syncthreads();

        #pragma unroll
        for (int p = 0; p < 4; ++p) {
            const int m = wmr + p * 32;
            float4 wv = *(const float4*)(W + (size_t)(m0 + m) * Cdim + k0 + wk4);
            ushort4 hi, lo;
            hi.x = f32_bf16_rne(wv.x); lo.x = f32_bf16_rne(wv.x - bf16_f32(hi.x));
            hi.y = f32_bf16_rne(wv.y); lo.y = f32_bf16_rne(wv.y - bf16_f32(hi.y));
            hi.z = f32_bf16_rne(wv.z); lo.z = f32_bf16_rne(wv.z - bf16_f32(hi.z));
            hi.w = f32_bf16_rne(wv.w); lo.w = f32_bf16_rne(wv.w - bf16_f32(hi.w));
            *(ushort4*)&Whi[m][wk4] = hi;
            *(ushort4*)&Wlo[m][wk4] = lo;
        }

        {
            float xv[8];
            #pragma unroll
            for (int kk = 0; kk < 8; ++kk)
                xv[kk] = Xb[(size_t)(k0 + xo * 8 + kk) * Tdim + n0 + xn];
            ushort4 hi0, hi1, lo0, lo1;
            unsigned short h;
            h = f32_bf16_rne(xv[0]); hi0.x = h; lo0.x = f32_bf16_rne(xv[0] - bf16_f32(h));
            h = f32_bf16_rne(xv[1]); hi0.y = h; lo0.y = f32_bf16_rne(xv[1] - bf16_f32(h));
            h = f32_bf16_rne(xv[2]); hi0.z = h; lo0.z = f32_bf16_rne(xv[2] - bf16_f32(h));
            h = f32_bf16_rne(xv[3]); hi0.w = h; lo0.w = f32_bf16_rne(xv[3] - bf16_f32(h));
            h = f32_bf16_rne(xv[4]); hi1.x = h; lo1.x = f32_bf16_rne(xv[4] - bf16_f32(h));
            h = f32_bf16_rne(xv[5]); hi1.y = h; lo1.y = f32_bf16_rne(xv[5] - bf16_f32(h));
            h = f32_bf16_rne(xv[6]); hi1.z = h; lo1.z = f32_bf16_rne(xv[6] - bf16_f32(h));
            h = f32_bf16_rne(xv[7]); hi1.w = h; lo1.w = f32_bf16_rne(xv[7] - bf16_f32(h));
            *(ushort4*)&Xhi[xn][xo * 8]     = hi0;
            *(ushort4*)&Xhi[xn][xo * 8 + 4] = hi1;
            *(ushort4*)&Xlo[xn][xo * 8]     = lo0;
            *(ushort4*)&Xlo[xn][xo * 8 + 4] = lo1;
        }
        __syncthreads();

        bf16x8 ahi[4], alo[4], bhi[2], blo[2];
        #pragma unroll
        for (int mt = 0; mt < 4; ++mt) {
            ahi[mt] = *(const bf16x8*)&Whi[wm + mt * 16 + l15][quad * 8];
            alo[mt] = *(const bf16x8*)&Wlo[wm + mt * 16 + l15][quad * 8];
        }
        #pragma unroll
        for (int nt = 0; nt < 2; ++nt) {
            bhi[nt] = *(const bf16x8*)&Xhi[wn + nt * 16 + l15][quad * 8];
            blo[nt] = *(const bf16x8*)&Xlo[wn + nt * 16 + l15][quad * 8];
        }
        #pragma unroll
        for (int mt = 0; mt < 4; ++mt)
            #pragma unroll
            for (int nt = 0; nt < 2; ++nt) {
                f32x4 c = acc[mt][nt];
                c = __builtin_amdgcn_mfma_f32_16x16x32_bf16(ahi[mt], bhi[nt], c, 0, 0, 0);
                c = __builtin_amdgcn_mfma_f32_16x16x32_bf16(ahi[mt], blo[nt], c, 0, 0, 0);
                c = __builtin_amdgcn_mfma_f32_16x16x32_bf16(alo[mt], bhi[nt], c, 0, 0, 0);
                acc[mt][nt] = c;
            }
    }

    // ---- epilogue ----
    if (mode == 1) {
        float* Ob = ofp + (size_t)b * Cdim * Tdim;
        #pragma unroll
        for (int mt = 0; mt < 4; ++mt) {
            const int mb = m0 + wm + mt * 16 + quad * 4;
            float bb[4];
            #pragma unroll
            for (int r = 0; r < 4; ++r) bb[r] = Bv[mb + r];
            #pragma unroll
            for (int nt = 0; nt < 2; ++nt) {
                const int t = n0 + wn + nt * 16 + l15;
                #pragma unroll
                for (int r = 0; r < 4; ++r)
                    Ob[(size_t)(mb + r) * Tdim + t] = acc[mt][nt][r] + bb[r];
            }
        }
    } else if (sel < 2) {
        // Q/K planes: frag-major row-type, ushort4 along c (c0 mult of 4)
        unsigned short* phi = sel == 0 ? qhi : khi;
        unsigned short* plo = sel == 0 ? qlo : klo;
        #pragma unroll
        for (int mt = 0; mt < 4; ++mt) {
            const int mv = m0 + wm + mt * 16 + quad * 4;
            const int head = mv >> 6, c0 = mv & 63;
            float bb[4];
            #pragma unroll
            for (int r = 0; r < 4; ++r) bb[r] = Bv[mv + r];
            #pragma unroll
            for (int nt = 0; nt < 2; ++nt) {
                const int t = n0 + wn + nt * 16 + l15;
                const int tile = t >> 6, r_ = t & 63;
                const size_t off = (((size_t)(b * Hn + head) * 16 + tile) << 12)
                                 + (size_t)off_row(r_, c0);
                ushort4 h4, l4;
                float v0 = acc[mt][nt][0] + bb[0];
                float v1 = acc[mt][nt][1] + bb[1];
                float v2 = acc[mt][nt][2] + bb[2];
                float v3 = acc[mt][nt][3] + bb[3];
                h4.x = f32_bf16_rne(v0); l4.x = f32_bf16_rne(v0 - bf16_f32(h4.x));
                h4.y = f32_bf16_rne(v1); l4.y = f32_bf16_rne(v1 - bf16_f32(h4.y));
                h4.z = f32_bf16_rne(v2); l4.z = f32_bf16_rne(v2 - bf16_f32(h4.z));
                h4.w = f32_bf16_rne(v3); l4.w = f32_bf16_rne(v3 - bf16_f32(h4.w));
                *(ushort4*)(phi + off) = h4;
                *(ushort4*)(plo + off) = l4;
            }
        }
    } else {
        // V planes: frag-major col-type -> per-element ushort stores
        #pragma unroll
        for (int mt = 0; mt < 4; ++mt) {
            const int mv = m0 + wm + mt * 16 + quad * 4;
            const int head = mv >> 6;
            float bb[4];
            #pragma unroll
            for (int r = 0; r < 4; ++r) bb[r] = Bv[mv + r];
            #pragma unroll
            for (int nt = 0; nt < 2; ++nt) {
                const int t = n0 + wn + nt * 16 + l15;
                const int tile = t >> 6, jl = t & 63;
                const size_t tb = ((size_t)(b * Hn + head) * 16 + tile) << 12;
                #pragma unroll
                for (int r = 0; r < 4; ++r) {
                    const int cr = (mv & 63) + r;
                    const float v = acc[mt][nt][r] + bb[r];
                    const unsigned short h = f32_bf16_rne(v);
                    const size_t off = tb + off_col(cr, jl);
                    vhi[off] = h;
                    vlo[off] = f32_bf16_rne(v - bf16_f32(h));
                }
            }
        }
    }
}

// ---------------------------------------------------------------------------
// Barrier-free MFMA flash attention, frag-major coalesced global frag loads.
// Every K/V/Q frag load: base + g*512 + lane*8 ushorts -> one coalesced
// global_load_dwordx4, loop-invariant offsets, per-tile scalar base add.
// P round-trip stays in LDS (intra-wave rows only, no barrier).
// ---------------------------------------------------------------------------
__global__ __launch_bounds__(256) void attn_mfma(
    const unsigned short* __restrict__ qhi, const unsigned short* __restrict__ qlo,
    const unsigned short* __restrict__ khi, const unsigned short* __restrict__ klo,
    const unsigned short* __restrict__ vhi, const unsigned short* __restrict__ vlo,
    const float* __restrict__ ek,   // [9,64]
    const float* __restrict__ ev,   // [9,64]
    float* __restrict__ ctx)        // [B,C,T]
{
    __shared__ alignas(16) unsigned short psh[4096], psl[4096];
    __shared__ float rk[576];       // [m][e], stride 9
    __shared__ float evs[576];      // [e][c]

    const int tid = threadIdx.x;

    // ---- XCD-clustered decode: 512 blocks, 64/XCD = 4 (b,h) x 16 i-tiles ----
    int it, h, b;
    {
        const int n = blockIdx.x;
        const int xcd = n & 7, slot = n >> 3;
        const int pair = (xcd << 2) | (slot >> 4);
        it = slot & 15;
        b = pair >> 3;
        h = pair & 7;
    }
    const int i0 = it * 64;
    const int lane = tid & 63, w = tid >> 6;
    const int l15 = lane & 15, quad = lane >> 4;
    const int m_blk = w * 16 + l15;
    const int lo8 = lane << 3;      // coalesced frag voffset (ushorts)

    const size_t bh16 = (size_t)(b * Hn + h) * 16;
    float* ctxb = ctx + ((size_t)b * Cdim + h * KCd) * Tdim;

    // ---- Q frags: coalesced from frag-major plane (one-time) ----
    bf16x8 qfh[2], qfl[2];
    {
        const unsigned short* qth = qhi + ((bh16 + it) << 12);
        const unsigned short* qtl = qlo + ((bh16 + it) << 12);
        #pragma unroll
        for (int ks = 0; ks < 2; ++ks) {
            qfh[ks] = *(const bf16x8*)(qth + (((w << 1) | ks) << 9) + lo8);
            qfl[ks] = *(const bf16x8*)(qtl + (((w << 1) | ks) << 9) + lo8);
        }
    }

    // ---- ek B-frags in registers (lanes l15>=9 zero) ----
    bf16x8 ekh[2], ekl[2];
    #pragma unroll
    for (int ks = 0; ks < 2; ++ks) {
        #pragma unroll
        for (int j = 0; j < 8; ++j) { ekh[ks][j] = 0; ekl[ks][j] = 0; }
        if (l15 < 9) {
            #pragma unroll
            for (int j = 0; j < 8; ++j) {
                const float v = ek[l15 * 64 + ks * 32 + quad * 8 + j];
                const unsigned short hh = f32_bf16_rne(v);
                ekh[ks][j] = (short)hh;
                ekl[ks][j] = (short)f32_bf16_rne(v - bf16_f32(hh));
            }
        }
    }

    // ---- rk[m][e] = q[m]·ek[e] via MFMA (raw, pre-scale) ----
    {
        f32x4 rkD = (f32x4){0.f, 0.f, 0.f, 0.f};
        #pragma unroll
        for (int ks = 0; ks < 2; ++ks) {
            rkD = __builtin_amdgcn_mfma_f32_16x16x32_bf16(qfh[ks], ekh[ks], rkD, 0, 0, 0);
            rkD = __builtin_amdgcn_mfma_f32_16x16x32_bf16(qfh[ks], ekl[ks], rkD, 0, 0, 0);
            rkD = __builtin_amdgcn_mfma_f32_16x16x32_bf16(qfl[ks], ekh[ks], rkD, 0, 0, 0);
        }
        if (l15 < 9) {
            #pragma unroll
            for (int r = 0; r < 4; ++r)
                rk[(w * 16 + quad * 4 + r) * 9 + l15] = rkD[r];
        }
    }
    for (int idx = tid; idx < 576; idx += 256) evs[idx] = ev[idx];
    __syncthreads();   // the ONLY barrier: rk/evs visible

    float m_run = -1e30f, l_run = 0.f;
    f32x4 Oc[4];
    #pragma unroll
    for (int ct = 0; ct < 4; ++ct) Oc[ct] = (f32x4){0.f, 0.f, 0.f, 0.f};

    const unsigned short* kh0 = khi + (bh16 << 12);
    const unsigned short* kl0 = klo + (bh16 << 12);
    const unsigned short* vh0 = vhi + (bh16 << 12);
    const unsigned short* vl0 = vlo + (bh16 << 12);

    for (int t = 0; t < 16; ++t) {
        const int j0 = t << 6;
        const size_t tb = (size_t)t << 12;
        const unsigned short* kht = kh0 + tb;
        const unsigned short* klt = kl0 + tb;
        const unsigned short* vht = vh0 + tb;
        const unsigned short* vlt = vl0 + tb;

        // ---- V frags issued first (latency hides under GEMM1 + softmax) ----
        bf16x8 vbh[2][4], vbl[2][4];
        #pragma unroll
        for (int ks = 0; ks < 2; ++ks)
            #pragma unroll
            for (int ct = 0; ct < 4; ++ct) {
                vbh[ks][ct] = *(const bf16x8*)(vht + (((ct << 1) | ks) << 9) + lo8);
                vbl[ks][ct] = *(const bf16x8*)(vlt + (((ct << 1) | ks) << 9) + lo8);
            }

        // ---- GEMM1: S^T[j][m], coalesced K frags ----
        f32x4 Sc[4];
        #pragma unroll
        for (int jt = 0; jt < 4; ++jt) Sc[jt] = (f32x4){0.f, 0.f, 0.f, 0.f};
        #pragma unroll
        for (int ks = 0; ks < 2; ++ks) {
            bf16x8 ah[4], al[4];
            #pragma unroll
            for (int jt = 0; jt < 4; ++jt) {
                ah[jt] = *(const bf16x8*)(kht + (((jt << 1) | ks) << 9) + lo8);
                al[jt] = *(const bf16x8*)(klt + (((jt << 1) | ks) << 9) + lo8);
            }
            #pragma unroll
            for (int jt = 0; jt < 4; ++jt) {
                Sc[jt] = __builtin_amdgcn_mfma_f32_16x16x32_bf16(ah[jt], qfh[ks], Sc[jt], 0, 0, 0);
                Sc[jt] = __builtin_amdgcn_mfma_f32_16x16x32_bf16(ah[jt], qfl[ks], Sc[jt], 0, 0, 0);
                Sc[jt] = __builtin_amdgcn_mfma_f32_16x16x32_bf16(al[jt], qfh[ks], Sc[jt], 0, 0, 0);
            }
        }

        const int dt = j0 - i0;
        const bool diag = (dt >= -67 && dt <= 67);
        if (diag) {
            #pragma unroll
            for (int jt = 0; jt < 4; ++jt) {
                const int db = dt + jt * 16 + quad * 4 - m_blk;
                #pragma unroll
                for (int r = 0; r < 4; ++r) {
                    const int d = db + r;
                    if ((unsigned)(d + 4) <= 8u) Sc[jt][r] += rk[m_blk * 9 + d + 4];
                }
            }
        }

        // ---- scale + online softmax (per-lane row m_blk) ----
        float mt = -1e30f;
        #pragma unroll
        for (int jt = 0; jt < 4; ++jt)
            #pragma unroll
            for (int r = 0; r < 4; ++r) {
                Sc[jt][r] *= 0.125f;
                mt = fmaxf(mt, Sc[jt][r]);
            }
        mt = fmaxf(mt, __shfl_xor(mt, 16));
        mt = fmaxf(mt, __shfl_xor(mt, 32));
        const float mn = fmaxf(m_run, mt);
        const float alpha = __expf(m_run - mn);
        float rs = 0.f;
        #pragma unroll
        for (int jt = 0; jt < 4; ++jt)
            #pragma unroll
            for (int r = 0; r < 4; ++r) {
                const float e = __expf(Sc[jt][r] - mn);
                Sc[jt][r] = e;
                rs += e;
            }
        rs += __shfl_xor(rs, 16);
        rs += __shfl_xor(rs, 32);
        l_run = l_run * alpha + rs;
        m_run = mn;

        // ---- write P (A-layout [m][j], hi/lo); intra-wave rows only ----
        #pragma unroll
        for (int jt = 0; jt < 4; ++jt) {
            ushort4 ph, pl;
            ph.x = f32_bf16_rne(Sc[jt][0]); pl.x = f32_bf16_rne(Sc[jt][0] - bf16_f32(ph.x));
            ph.y = f32_bf16_rne(Sc[jt][1]); pl.y = f32_bf16_rne(Sc[jt][1] - bf16_f32(ph.y));
            ph.z = f32_bf16_rne(Sc[jt][2]); pl.z = f32_bf16_rne(Sc[jt][2] - bf16_f32(ph.z));
            ph.w = f32_bf16_rne(Sc[jt][3]); pl.w = f32_bf16_rne(Sc[jt][3] - bf16_f32(ph.w));
            const int o = sw(m_blk, jt * 16 + quad * 4);
            *(ushort4*)&psh[o] = ph;
            *(ushort4*)&psl[o] = pl;
        }
        // no barrier: wave w reads only rows [16w,16w+16) which it just wrote

        // ---- GEMM2: O[m][c] += P·V ----
        const float al0 = __shfl(alpha, quad * 4 + 0);
        const float al1 = __shfl(alpha, quad * 4 + 1);
        const float al2 = __shfl(alpha, quad * 4 + 2);
        const float al3 = __shfl(alpha, quad * 4 + 3);
        #pragma unroll
        for (int ct = 0; ct < 4; ++ct) {
            Oc[ct][0] *= al0; Oc[ct][1] *= al1; Oc[ct][2] *= al2; Oc[ct][3] *= al3;
        }
        #pragma unroll
        for (int ks = 0; ks < 2; ++ks) {
            bf16x8 pah = fragld(psh, m_blk, ks, quad);
            bf16x8 pal = fragld(psl, m_blk, ks, quad);
            #pragma unroll
            for (int ct = 0; ct < 4; ++ct) {
                Oc[ct] = __builtin_amdgcn_mfma_f32_16x16x32_bf16(pah, vbh[ks][ct], Oc[ct], 0, 0, 0);
                Oc[ct] = __builtin_amdgcn_mfma_f32_16x16x32_bf16(pah, vbl[ks][ct], Oc[ct], 0, 0, 0);
                Oc[ct] = __builtin_amdgcn_mfma_f32_16x16x32_bf16(pal, vbh[ks][ct], Oc[ct], 0, 0, 0);
            }
        }

        if (diag) {   // banded rel-v via P in LDS (own wave's rows)
            #pragma unroll
            for (int r = 0; r < 4; ++r) {
                const int mrow = w * 16 + quad * 4 + r;
                const int ig = i0 + mrow;
                #pragma unroll
                for (int e = 0; e < 9; ++e) {
                    const int jl = ig + e - 4 - j0;
                    if ((unsigned)jl < 64u) {
                        const int o = sw(mrow, jl);
                        const float p = bf16_f32(psh[o]) + bf16_f32(psl[o]);
                        #pragma unroll
                        for (int ct = 0; ct < 4; ++ct)
                            Oc[ct][r] += p * evs[e * 64 + ct * 16 + l15];
                    }
                }
            }
        }
    }

    // ---- epilogue: normalize rows, store ctx natural [B,C,T] ----
    const float rlv = 1.f / l_run;
    const float rl0 = __shfl(rlv, quad * 4 + 0);
    const float rl1 = __shfl(rlv, quad * 4 + 1);
    const float rl2 = __shfl(rlv, quad * 4 + 2);
    const float rl3 = __shfl(rlv, quad * 4 + 3);
    #pragma unroll
    for (int ct = 0; ct < 4; ++ct) {
        float4 o4;
        o4.x = Oc[ct][0] * rl0;
        o4.y = Oc[ct][1] * rl1;
        o4.z = Oc[ct][2] * rl2;
        o4.w = Oc[ct][3] * rl3;
        *(float4*)(ctxb + (size_t)(ct * 16 + l15) * Tdim + i0 + w * 16 + quad * 4) = o4;
    }
}

// ---------------------------------------------------------------------------
extern "C" void kernel_launch(void* const* d_in, const int* in_sizes, int n_in,
                              void* d_out, int out_size, void* d_ws, size_t ws_size,
                              hipStream_t stream) {
    const float* x  = (const float*)d_in[0];
    const float* wq = (const float*)d_in[1];
    const float* bq = (const float*)d_in[2];
    const float* wk = (const float*)d_in[3];
    const float* bk = (const float*)d_in[4];
    const float* wv = (const float*)d_in[5];
    const float* bv = (const float*)d_in[6];
    const float* wo = (const float*)d_in[7];
    const float* bo = (const float*)d_in[8];
    const float* ek = (const float*)d_in[9];
    const float* ev = (const float*)d_in[10];
    float* out = (float*)d_out;

    const size_t plane = (size_t)Bdim * Cdim * Tdim;  // 2M elements
    unsigned short* qhi = (unsigned short*)d_ws;
    unsigned short* qlo = qhi + plane;
    unsigned short* khi = qlo + plane;
    unsigned short* klo = khi + plane;
    unsigned short* vhi = klo + plane;
    unsigned short* vlo = vhi + plane;
    float* cbuf = (float*)(vlo + plane);              // 8 MB fp32

    // QKV projection -> pre-split frag-major bf16 planes
    gemm3_mfma<<<dim3(768), 256, 0, stream>>>(
        0, wq, wk, wv, bq, bk, bv, x, qhi, qlo, khi, klo, vhi, vlo, nullptr);

    // barrier-free MFMA flash attention with banded relative terms
    attn_mfma<<<dim3(512), 256, 0, stream>>>(
        qhi, qlo, khi, klo, vhi, vlo, ek, ev, cbuf);

    // output projection (natural fp32 store)
    gemm3_mfma<<<dim3(256), 256, 0, stream>>>(
        1, wo, wo, wo, bo, bo, bo, cbuf,
        nullptr, nullptr, nullptr, nullptr, nullptr, nullptr, out);
}